// Round 1
// baseline (1720.050 us; speedup 1.0000x reference)
//
#include <hip/hip_runtime.h>

#define NN 50000
#define NE 400000
#define NG 64

// ---------------- GEMM1: X[NN,512] @ {Wa,Wb}[512,128] -> Ya,Yb [NN,128] ----------------
// 16 rows per block, 256 threads: t<128 -> Wa col t, t>=128 -> Wb col t-128.
// x tile staged row-major in LDS (32KB), read as broadcast ds_read_b128 (4 k at a time).
__global__ __launch_bounds__(256) void gemm1_k(const float* __restrict__ X,
                                               const float* __restrict__ Wa,
                                               const float* __restrict__ Wb,
                                               float* __restrict__ Ya,
                                               float* __restrict__ Yb) {
    __shared__ float xt[16 * 512];
    const int t = threadIdx.x;
    const int row0 = blockIdx.x * 16;
    {
        const float4* xv = (const float4*)(X + (size_t)row0 * 512);
        float4* xs = (float4*)xt;
#pragma unroll
        for (int i = 0; i < 8; i++) xs[t + 256 * i] = xv[t + 256 * i];
    }
    __syncthreads();
    const float* W = (t < 128) ? Wa : Wb;
    float* Y = (t < 128) ? Ya : Yb;
    const int col = t & 127;
    float acc[16];
#pragma unroll
    for (int r = 0; r < 16; r++) acc[r] = 0.f;
    for (int k = 0; k < 512; k += 4) {
        const float w0 = W[(k + 0) * 128 + col];
        const float w1 = W[(k + 1) * 128 + col];
        const float w2 = W[(k + 2) * 128 + col];
        const float w3 = W[(k + 3) * 128 + col];
#pragma unroll
        for (int r = 0; r < 16; r++) {
            const float4 xr = *(const float4*)(xt + r * 512 + k);
            acc[r] = fmaf(xr.x, w0, fmaf(xr.y, w1, fmaf(xr.z, w2, fmaf(xr.w, w3, acc[r]))));
        }
    }
#pragma unroll
    for (int r = 0; r < 16; r++) Y[(size_t)(row0 + r) * 128 + col] = acc[r];
}

// ---------------- GEMM2: X[NN,128] @ {Wa,Wb}[128,32] -> Ya,Yb [NN,32] ----------------
// 16 rows per block, 256 threads: (t&63)<32 -> Wa, else Wb; rowgroup = t>>6 handles 4 rows.
__global__ __launch_bounds__(256) void gemm2_k(const float* __restrict__ X,
                                               const float* __restrict__ Wa,
                                               const float* __restrict__ Wb,
                                               float* __restrict__ Ya,
                                               float* __restrict__ Yb) {
    __shared__ float xt[16 * 128];
    const int t = threadIdx.x;
    const int row0 = blockIdx.x * 16;
    {
        const float4* xv = (const float4*)(X + (size_t)row0 * 128);
        float4* xs = (float4*)xt;
#pragma unroll
        for (int i = 0; i < 2; i++) xs[t + 256 * i] = xv[t + 256 * i];
    }
    __syncthreads();
    const int c64 = t & 63;
    const float* W = (c64 < 32) ? Wa : Wb;
    float* Y = (c64 < 32) ? Ya : Yb;
    const int col = c64 & 31;
    const int rg = t >> 6;  // 0..3
    float acc[4] = {0.f, 0.f, 0.f, 0.f};
    for (int k = 0; k < 128; k += 4) {
        const float w0 = W[(k + 0) * 32 + col];
        const float w1 = W[(k + 1) * 32 + col];
        const float w2 = W[(k + 2) * 32 + col];
        const float w3 = W[(k + 3) * 32 + col];
#pragma unroll
        for (int r = 0; r < 4; r++) {
            const float4 xr = *(const float4*)(xt + (rg * 4 + r) * 128 + k);
            acc[r] = fmaf(xr.x, w0, fmaf(xr.y, w1, fmaf(xr.z, w2, fmaf(xr.w, w3, acc[r]))));
        }
    }
#pragma unroll
    for (int r = 0; r < 4; r++) Y[(size_t)(row0 + rg * 4 + r) * 32 + col] = acc[r];
}

// ---------------- in-degree count ----------------
__global__ void cnt_k(const int* __restrict__ dst, float* __restrict__ cnt) {
    const int e = blockIdx.x * 256 + threadIdx.x;
    if (e < NE) atomicAdd(&cnt[dst[e]], 1.0f);
}

// ---------------- scatter: agg[dst[e]] += Y[src[e]]  (F4 float4-chunks per row) --------
template <int F4>
__global__ void scatter_k(const float* __restrict__ Y, const int* __restrict__ src,
                          const int* __restrict__ dst, float* __restrict__ agg) {
    const int gid = blockIdx.x * 256 + threadIdx.x;
    const int e = gid / F4;
    const int f = gid % F4;
    const int s = src[e];
    const int d = dst[e];
    const float4 v = ((const float4*)(Y + (size_t)s * (F4 * 4)))[f];
    float* a = agg + (size_t)d * (F4 * 4) + f * 4;
    atomicAdd(a + 0, v.x);
    atomicAdd(a + 1, v.y);
    atomicAdd(a + 2, v.z);
    atomicAdd(a + 3, v.w);
}

// ---------------- h = relu(agg/cnt + b + yr) ----------------
template <int F4>
__global__ void hpost_k(const float* __restrict__ agg, const float* __restrict__ cnt,
                        const float* __restrict__ b, const float* __restrict__ yr,
                        float* __restrict__ h, int total) {
    const int gid = blockIdx.x * 256 + threadIdx.x;
    if (gid >= total) return;
    const int i = gid / F4;
    const int f = gid % F4;
    const float inv = 1.f / fmaxf(cnt[i], 1.f);
    const float4 a = ((const float4*)agg)[gid];
    const float4 y = ((const float4*)yr)[gid];
    const float4 bb = ((const float4*)b)[f];
    float4 o;
    o.x = fmaxf(fmaf(a.x, inv, bb.x + y.x), 0.f);
    o.y = fmaxf(fmaf(a.y, inv, bb.y + y.y), 0.f);
    o.z = fmaxf(fmaf(a.z, inv, bb.z + y.z), 0.f);
    o.w = fmaxf(fmaf(a.w, inv, bb.w + y.w), 0.f);
    ((float4*)h)[gid] = o;
}

// ---------------- global mean pool: gsum[batch[i]] += h2[i] ----------------
__global__ void pool_k(const float* __restrict__ h2, const int* __restrict__ batch,
                       float* __restrict__ gsum, float* __restrict__ gcnt) {
    const int gid = blockIdx.x * 256 + threadIdx.x;  // NN*32 exact
    const int i = gid >> 5;
    const int f = gid & 31;
    const int g = batch[i];
    atomicAdd(&gsum[g * 32 + f], h2[gid]);
    if (f == 0) atomicAdd(&gcnt[g], 1.f);
}

__device__ __forceinline__ float leaky(float v) { return v > 0.f ? v : 0.1f * v; }

// ---------------- final tiny MLP: one wave, thread = graph ----------------
__global__ __launch_bounds__(64) void finale_k(const float* __restrict__ gsum,
                                               const float* __restrict__ gcnt,
                                               const float* __restrict__ Wl1, const float* __restrict__ bl1,
                                               const float* __restrict__ Wl2, const float* __restrict__ bl2,
                                               const float* __restrict__ Wd1, const float* __restrict__ bd1,
                                               const float* __restrict__ Wd2, const float* __restrict__ bd2,
                                               const float* __restrict__ Wd3, const float* __restrict__ bd3,
                                               float* __restrict__ out) {
    const int g = threadIdx.x;  // 0..63
    const float inv = 1.f / fmaxf(gcnt[g], 1.f);
    float v[32];
#pragma unroll
    for (int f = 0; f < 32; f++) v[f] = gsum[g * 32 + f] * inv;
    float t1[32];
#pragma unroll
    for (int n = 0; n < 32; n++) {
        float s = bl1[n];
#pragma unroll
        for (int k = 0; k < 32; k++) s = fmaf(v[k], Wl1[k * 32 + n], s);
        t1[n] = fmaxf(s, 0.f);
    }
    float e[16];
#pragma unroll
    for (int n = 0; n < 16; n++) {
        float s = bl2[n];
#pragma unroll
        for (int k = 0; k < 32; k++) s = fmaf(t1[k], Wl2[k * 16 + n], s);
        e[n] = leaky(s);
        out[g * 16 + n] = e[n];
    }
    float z1[32];
#pragma unroll
    for (int n = 0; n < 32; n++) {
        float s = bd1[n];
#pragma unroll
        for (int k = 0; k < 16; k++) s = fmaf(e[k], Wd1[k * 32 + n], s);
        z1[n] = leaky(s);
    }
    float z2[32];
#pragma unroll
    for (int n = 0; n < 32; n++) {
        float s = bd2[n];
#pragma unroll
        for (int k = 0; k < 32; k++) s = fmaf(z1[k], Wd2[k * 32 + n], s);
        z2[n] = leaky(s);
    }
#pragma unroll
    for (int n = 0; n < 50; n++) {
        float s = bd3[n];
#pragma unroll
        for (int k = 0; k < 32; k++) s = fmaf(z2[k], Wd3[k * 50 + n], s);
        out[1024 + g * 50 + n] = s;
    }
}

extern "C" void kernel_launch(void* const* d_in, const int* in_sizes, int n_in,
                              void* d_out, int out_size, void* d_ws, size_t ws_size,
                              hipStream_t stream) {
    const float* x = (const float*)d_in[0];
    const int* ei = (const int*)d_in[1];
    const int* src = ei;
    const int* dst = ei + NE;
    const int* batch = (const int*)d_in[2];
    const float* W1l = (const float*)d_in[3];
    const float* b1l = (const float*)d_in[4];
    const float* W1r = (const float*)d_in[5];
    const float* W2l = (const float*)d_in[6];
    const float* b2l = (const float*)d_in[7];
    const float* W2r = (const float*)d_in[8];
    const float* Wl1 = (const float*)d_in[9];
    const float* bl1 = (const float*)d_in[10];
    const float* Wl2 = (const float*)d_in[11];
    const float* bl2 = (const float*)d_in[12];
    const float* Wd1 = (const float*)d_in[13];
    const float* bd1 = (const float*)d_in[14];
    const float* Wd2 = (const float*)d_in[15];
    const float* bd2 = (const float*)d_in[16];
    const float* Wd3 = (const float*)d_in[17];
    const float* bd3 = (const float*)d_in[18];

    float* ws = (float*)d_ws;
    // region A: y1l, later reused as h1
    float* y1l = ws;                   // NN*128 = 6.4M floats
    float* h1 = y1l;
    // region B: y1r
    float* y1r = ws + 6400000;         // 6.4M
    // region C: agg1, later reused for layer-2 buffers
    float* agg1 = ws + 12800000;       // 6.4M
    float* y2l = agg1;                 // NN*32 = 1.6M
    float* y2r = agg1 + 1600000;
    float* agg2 = agg1 + 3200000;
    float* h2 = agg1 + 4800000;
    // region D: cnt, gsum, gcnt
    float* cnt = ws + 19200000;        // 50000
    float* gsum = cnt + 50000;         // 64*32
    float* gcnt = gsum + 2048;         // 64

    // zero accumulators
    hipMemsetAsync(agg1, 0, (size_t)6400000 * 4, stream);
    hipMemsetAsync(cnt, 0, (size_t)(50000 + 2048 + 64) * 4, stream);

    // layer 1
    gemm1_k<<<3125, 256, 0, stream>>>(x, W1l, W1r, y1l, y1r);
    cnt_k<<<1563, 256, 0, stream>>>(dst, cnt);
    scatter_k<32><<<50000, 256, 0, stream>>>(y1l, src, dst, agg1);  // NE*32/256
    hpost_k<32><<<6250, 256, 0, stream>>>(agg1, cnt, b1l, y1r, h1, NN * 32);

    // layer 2 (buffers alias dead agg1 region; stream-ordered so safe)
    gemm2_k<<<3125, 256, 0, stream>>>(h1, W2l, W2r, y2l, y2r);
    hipMemsetAsync(agg2, 0, (size_t)1600000 * 4, stream);
    scatter_k<8><<<12500, 256, 0, stream>>>(y2l, src, dst, agg2);   // NE*8/256
    hpost_k<8><<<1563, 256, 0, stream>>>(agg2, cnt, b2l, y2r, h2, NN * 8);

    // pooling + MLP head
    pool_k<<<6250, 256, 0, stream>>>(h2, batch, gsum, gcnt);
    finale_k<<<1, 64, 0, stream>>>(gsum, gcnt, Wl1, bl1, Wl2, bl2,
                                   Wd1, bd1, Wd2, bd2, Wd3, bd3, (float*)d_out);
}

// Round 2
// 686.628 us; speedup vs baseline: 2.5051x; 2.5051x over previous
//
#include <hip/hip_runtime.h>

#define NN 50000
#define NE 400000
#define NG 64

// ---------------- GEMM1: X[NN,512] @ {Wa,Wb}[512,128] -> Ya,Yb [NN,128] ----------------
__global__ __launch_bounds__(256) void gemm1_k(const float* __restrict__ X,
                                               const float* __restrict__ Wa,
                                               const float* __restrict__ Wb,
                                               float* __restrict__ Ya,
                                               float* __restrict__ Yb) {
    __shared__ float xt[16 * 512];
    const int t = threadIdx.x;
    const int row0 = blockIdx.x * 16;
    {
        const float4* xv = (const float4*)(X + (size_t)row0 * 512);
        float4* xs = (float4*)xt;
#pragma unroll
        for (int i = 0; i < 8; i++) xs[t + 256 * i] = xv[t + 256 * i];
    }
    __syncthreads();
    const float* W = (t < 128) ? Wa : Wb;
    float* Y = (t < 128) ? Ya : Yb;
    const int col = t & 127;
    float acc[16];
#pragma unroll
    for (int r = 0; r < 16; r++) acc[r] = 0.f;
    for (int k = 0; k < 512; k += 4) {
        const float w0 = W[(k + 0) * 128 + col];
        const float w1 = W[(k + 1) * 128 + col];
        const float w2 = W[(k + 2) * 128 + col];
        const float w3 = W[(k + 3) * 128 + col];
#pragma unroll
        for (int r = 0; r < 16; r++) {
            const float4 xr = *(const float4*)(xt + r * 512 + k);
            acc[r] = fmaf(xr.x, w0, fmaf(xr.y, w1, fmaf(xr.z, w2, fmaf(xr.w, w3, acc[r]))));
        }
    }
#pragma unroll
    for (int r = 0; r < 16; r++) Y[(size_t)(row0 + r) * 128 + col] = acc[r];
}

// ---------------- GEMM2: X[NN,128] @ {Wa,Wb}[128,32] -> Ya,Yb [NN,32] ----------------
__global__ __launch_bounds__(256) void gemm2_k(const float* __restrict__ X,
                                               const float* __restrict__ Wa,
                                               const float* __restrict__ Wb,
                                               float* __restrict__ Ya,
                                               float* __restrict__ Yb) {
    __shared__ float xt[16 * 128];
    const int t = threadIdx.x;
    const int row0 = blockIdx.x * 16;
    {
        const float4* xv = (const float4*)(X + (size_t)row0 * 128);
        float4* xs = (float4*)xt;
#pragma unroll
        for (int i = 0; i < 2; i++) xs[t + 256 * i] = xv[t + 256 * i];
    }
    __syncthreads();
    const int c64 = t & 63;
    const float* W = (c64 < 32) ? Wa : Wb;
    float* Y = (c64 < 32) ? Ya : Yb;
    const int col = c64 & 31;
    const int rg = t >> 6;  // 0..3
    float acc[4] = {0.f, 0.f, 0.f, 0.f};
    for (int k = 0; k < 128; k += 4) {
        const float w0 = W[(k + 0) * 32 + col];
        const float w1 = W[(k + 1) * 32 + col];
        const float w2 = W[(k + 2) * 32 + col];
        const float w3 = W[(k + 3) * 32 + col];
#pragma unroll
        for (int r = 0; r < 4; r++) {
            const float4 xr = *(const float4*)(xt + (rg * 4 + r) * 128 + k);
            acc[r] = fmaf(xr.x, w0, fmaf(xr.y, w1, fmaf(xr.z, w2, fmaf(xr.w, w3, acc[r]))));
        }
    }
#pragma unroll
    for (int r = 0; r < 4; r++) Y[(size_t)(row0 + rg * 4 + r) * 32 + col] = acc[r];
}

// ---------------- CSR build ----------------
__global__ void cnt_k(const int* __restrict__ dst, int* __restrict__ cnt) {
    const int e = blockIdx.x * 256 + threadIdx.x;
    if (e < NE) atomicAdd(&cnt[dst[e]], 1);
}

// exclusive scan of cnt[NN] -> rs[NN+1], single block of 1024
__global__ __launch_bounds__(1024) void scan_k(const int* __restrict__ cnt, int* __restrict__ rs) {
    __shared__ int part[1024];
    const int t = threadIdx.x;
    const int base = t * 49;
    int s = 0;
#pragma unroll 7
    for (int i = 0; i < 49; i++) {
        const int idx = base + i;
        if (idx < NN) s += cnt[idx];
    }
    part[t] = s;
    __syncthreads();
    for (int off = 1; off < 1024; off <<= 1) {
        const int v = (t >= off) ? part[t - off] : 0;
        __syncthreads();
        part[t] += v;
        __syncthreads();
    }
    int prefix = (t == 0) ? 0 : part[t - 1];
    for (int i = 0; i < 49; i++) {
        const int idx = base + i;
        if (idx < NN) {
            rs[idx] = prefix;
            prefix += cnt[idx];
        }
    }
    if (t == 1023) rs[NN] = prefix;
}

__global__ void place_k(const int* __restrict__ src, const int* __restrict__ dst,
                        const int* __restrict__ rs, int* __restrict__ cursor,
                        int* __restrict__ elist) {
    const int e = blockIdx.x * 256 + threadIdx.x;
    if (e < NE) {
        const int d = dst[e];
        const int p = atomicAdd(&cursor[d], 1);
        elist[rs[d] + p] = src[e];
    }
}

// ---------------- gather1: h1[n] = relu(mean_{s->n} y1l[s] + b + y1r[n]) ----------------
// one wave per node; h1 may alias y1r (each wave reads y1r[n] before writing h1[n] only).
__global__ __launch_bounds__(256) void gather1_k(const float* __restrict__ y1l,
                                                 const float* y1r,
                                                 const int* __restrict__ rs,
                                                 const int* __restrict__ elist,
                                                 const float* __restrict__ b,
                                                 float* h1) {
    const int t = threadIdx.x;
    const int n = blockIdx.x * 4 + (t >> 6);
    const int lane = t & 63;
    const int s0 = rs[n], s1 = rs[n + 1];
    float a0 = 0.f, a1 = 0.f;
    for (int j = s0; j < s1; j++) {
        const int s = elist[j];
        const float* r = y1l + (size_t)s * 128;
        a0 += r[lane];
        a1 += r[64 + lane];
    }
    const float inv = 1.f / fmaxf((float)(s1 - s0), 1.f);
    const size_t o = (size_t)n * 128;
    const float r0 = b[lane] + y1r[o + lane];
    const float r1 = b[64 + lane] + y1r[o + 64 + lane];
    h1[o + lane] = fmaxf(fmaf(a0, inv, r0), 0.f);
    h1[o + 64 + lane] = fmaxf(fmaf(a1, inv, r1), 0.f);
}

// ---------------- gather2: 32-dim version, half-wave per node ----------------
__global__ __launch_bounds__(256) void gather2_k(const float* __restrict__ y2l,
                                                 const float* y2r,
                                                 const int* __restrict__ rs,
                                                 const int* __restrict__ elist,
                                                 const float* __restrict__ b,
                                                 float* h2) {
    const int t = threadIdx.x;
    const int n = blockIdx.x * 8 + (t >> 5);
    const int lane = t & 31;
    const int s0 = rs[n], s1 = rs[n + 1];
    float a = 0.f;
    for (int j = s0; j < s1; j++) {
        const int s = elist[j];
        a += y2l[(size_t)s * 32 + lane];
    }
    const float inv = 1.f / fmaxf((float)(s1 - s0), 1.f);
    const size_t o = (size_t)n * 32;
    h2[o + lane] = fmaxf(fmaf(a, inv, b[lane] + y2r[o + lane]), 0.f);
}

__device__ __forceinline__ float leaky(float v) { return v > 0.f ? v : 0.1f * v; }

// ---------------- pool + MLP head, one block per graph ----------------
__global__ __launch_bounds__(256) void poolmlp_k(const float* __restrict__ h2,
                                                 const int* __restrict__ batch,
                                                 const float* __restrict__ Wl1, const float* __restrict__ bl1,
                                                 const float* __restrict__ Wl2, const float* __restrict__ bl2,
                                                 const float* __restrict__ Wd1, const float* __restrict__ bd1,
                                                 const float* __restrict__ Wd2, const float* __restrict__ bd2,
                                                 const float* __restrict__ Wd3, const float* __restrict__ bd3,
                                                 float* __restrict__ out) {
    __shared__ float red[256];
    __shared__ float bufA[32];
    __shared__ float bufB[32];
    const int g = blockIdx.x;
    const int t = threadIdx.x;
    // lower_bound boundaries in sorted batch[]
    int s, e;
    {
        int lo = 0, hi = NN;
        while (lo < hi) { const int m = (lo + hi) >> 1; if (batch[m] < g) lo = m + 1; else hi = m; }
        s = lo;
        lo = 0; hi = NN;
        while (lo < hi) { const int m = (lo + hi) >> 1; if (batch[m] < g + 1) lo = m + 1; else hi = m; }
        e = lo;
    }
    const int f = t & 31, grp = t >> 5;
    float acc = 0.f;
    for (int n = s + grp; n < e; n += 8) acc += h2[(size_t)n * 32 + f];
    red[t] = acc;
    __syncthreads();
    if (t < 32) {
        float sum = 0.f;
#pragma unroll
        for (int k = 0; k < 8; k++) sum += red[f + 32 * k];
        bufA[f] = sum / fmaxf((float)(e - s), 1.f);
    }
    __syncthreads();
    // t1 = relu(v@Wl1+bl1) -> bufB
    if (t < 32) {
        float sacc = bl1[t];
#pragma unroll
        for (int k = 0; k < 32; k++) sacc = fmaf(bufA[k], Wl1[k * 32 + t], sacc);
        bufB[t] = fmaxf(sacc, 0.f);
    }
    __syncthreads();
    // encoded = leaky(t1@Wl2+bl2) -> bufA[0..16), also to out
    if (t < 16) {
        float sacc = bl2[t];
#pragma unroll
        for (int k = 0; k < 32; k++) sacc = fmaf(bufB[k], Wl2[k * 16 + t], sacc);
        const float ev = leaky(sacc);
        bufA[t] = ev;
        out[g * 16 + t] = ev;
    }
    __syncthreads();
    // z1 = leaky(e@Wd1+bd1) -> bufB
    if (t < 32) {
        float sacc = bd1[t];
#pragma unroll
        for (int k = 0; k < 16; k++) sacc = fmaf(bufA[k], Wd1[k * 32 + t], sacc);
        bufB[t] = leaky(sacc);
    }
    __syncthreads();
    // z2 = leaky(z1@Wd2+bd2) -> bufA
    if (t < 32) {
        float sacc = bd2[t];
#pragma unroll
        for (int k = 0; k < 32; k++) sacc = fmaf(bufB[k], Wd2[k * 32 + t], sacc);
        bufA[t] = leaky(sacc);
    }
    __syncthreads();
    // reconstructed = z2@Wd3+bd3
    if (t < 50) {
        float sacc = bd3[t];
#pragma unroll
        for (int k = 0; k < 32; k++) sacc = fmaf(bufA[k], Wd3[k * 50 + t], sacc);
        out[1024 + g * 50 + t] = sacc;
    }
}

extern "C" void kernel_launch(void* const* d_in, const int* in_sizes, int n_in,
                              void* d_out, int out_size, void* d_ws, size_t ws_size,
                              hipStream_t stream) {
    const float* x = (const float*)d_in[0];
    const int* ei = (const int*)d_in[1];
    const int* src = ei;
    const int* dst = ei + NE;
    const int* batch = (const int*)d_in[2];
    const float* W1l = (const float*)d_in[3];
    const float* b1l = (const float*)d_in[4];
    const float* W1r = (const float*)d_in[5];
    const float* W2l = (const float*)d_in[6];
    const float* b2l = (const float*)d_in[7];
    const float* W2r = (const float*)d_in[8];
    const float* Wl1 = (const float*)d_in[9];
    const float* bl1 = (const float*)d_in[10];
    const float* Wl2 = (const float*)d_in[11];
    const float* bl2 = (const float*)d_in[12];
    const float* Wd1 = (const float*)d_in[13];
    const float* bd1 = (const float*)d_in[14];
    const float* Wd2 = (const float*)d_in[15];
    const float* bd2 = (const float*)d_in[16];
    const float* Wd3 = (const float*)d_in[17];
    const float* bd3 = (const float*)d_in[18];

    float* ws = (float*)d_ws;
    // float regions
    float* y1l = ws;                 // [0, 6.4M)
    float* y1r = ws + 6400000;       // [6.4M, 12.8M)  — h1 aliases (safe: per-node read-then-write)
    float* h1 = y1r;
    float* y2l = ws + 12800000;      // 1.6M
    float* y2r = ws + 14400000;      // 1.6M — h2 aliases
    float* h2 = y2r;
    // int region after 16M floats
    int* rs = (int*)(ws + 16000000);     // NN+1
    int* cursor = rs + (NN + 1);         // NN
    int* elist = cursor + NN;            // NE

    // --- CSR build ---
    hipMemsetAsync(cursor, 0, (size_t)NN * 4, stream);
    cnt_k<<<(NE + 255) / 256, 256, 0, stream>>>(dst, cursor);
    scan_k<<<1, 1024, 0, stream>>>(cursor, rs);
    hipMemsetAsync(cursor, 0, (size_t)NN * 4, stream);
    place_k<<<(NE + 255) / 256, 256, 0, stream>>>(src, dst, rs, cursor, elist);

    // --- layer 1 ---
    gemm1_k<<<3125, 256, 0, stream>>>(x, W1l, W1r, y1l, y1r);
    gather1_k<<<12500, 256, 0, stream>>>(y1l, y1r, rs, elist, b1l, h1);

    // --- layer 2 ---
    gemm2_k<<<3125, 256, 0, stream>>>(h1, W2l, W2r, y2l, y2r);
    gather2_k<<<6250, 256, 0, stream>>>(y2l, y2r, rs, elist, b2l, h2);

    // --- pool + MLP head ---
    poolmlp_k<<<NG, 256, 0, stream>>>(h2, batch, Wl1, bl1, Wl2, bl2,
                                      Wd1, bd1, Wd2, bd2, Wd3, bd3, (float*)d_out);
}

// Round 3
// 496.280 us; speedup vs baseline: 3.4659x; 1.3836x over previous
//
#include <hip/hip_runtime.h>

#define NN 50000
#define NE 400000
#define NG 64

typedef unsigned short u16;
typedef unsigned int u32;
typedef short short8 __attribute__((ext_vector_type(8)));
typedef float floatx4 __attribute__((ext_vector_type(4)));

__device__ __forceinline__ u16 f2bf(float f) {  // RNE
    union { float f; u32 u; } v; v.f = f;
    return (u16)((v.u + 0x7fff + ((v.u >> 16) & 1)) >> 16);
}
__device__ __forceinline__ float bflo(u32 p) { union { u32 u; float f; } v; v.u = p << 16; return v.f; }
__device__ __forceinline__ float bfhi(u32 p) { union { u32 u; float f; } v; v.u = p & 0xffff0000u; return v.f; }

#define GLD16(g, l) __builtin_amdgcn_global_load_lds( \
    (const __attribute__((address_space(1))) void*)(g), \
    (__attribute__((address_space(3))) void*)(l), 16, 0, 0)

// ---------------- cast x (fp32) -> xb (bf16), 8 elems/thread ----------------
__global__ __launch_bounds__(256) void cast_k(const float* __restrict__ x, u16* __restrict__ xb) {
    const int gid = blockIdx.x * 256 + threadIdx.x;  // 3.2M threads
    const float4* xv = (const float4*)x;
    const float4 a = xv[gid * 2], b = xv[gid * 2 + 1];
    u32 o[4];
    o[0] = f2bf(a.x) | ((u32)f2bf(a.y) << 16);
    o[1] = f2bf(a.z) | ((u32)f2bf(a.w) << 16);
    o[2] = f2bf(b.x) | ((u32)f2bf(b.y) << 16);
    o[3] = f2bf(b.z) | ((u32)f2bf(b.w) << 16);
    ((uint4*)xb)[gid] = *(const uint4*)o;
}

// ---------------- pack W1l|W1r (512x128 each, fp32) -> Wt1[256 cols][512 k] bf16 ------
__global__ __launch_bounds__(256) void prepw1_k(const float* __restrict__ Wl,
                                                const float* __restrict__ Wr,
                                                u16* __restrict__ Wt) {
    const int gid = blockIdx.x * 256 + threadIdx.x;  // 131072
    const int c = gid >> 9, k = gid & 511;
    const float v = (c < 128) ? Wl[k * 128 + c] : Wr[k * 128 + (c - 128)];
    Wt[gid] = f2bf(v);
}

// ---------------- pack W2l|W2r (128x32 each) -> Wt2[64 cols][128 k] bf16 ----------------
__global__ __launch_bounds__(256) void prepw2_k(const float* __restrict__ Wl,
                                                const float* __restrict__ Wr,
                                                u16* __restrict__ Wt) {
    const int gid = blockIdx.x * 256 + threadIdx.x;  // 8192
    const int c = gid >> 7, k = gid & 127;
    const float v = (c < 32) ? Wl[k * 32 + c] : Wr[k * 32 + (c - 32)];
    Wt[gid] = f2bf(v);
}

// ---------------- GEMM1 (MFMA): xb[NN,512] @ Wt1^T -> y1[NN,256] bf16 ----------------
// tile 128x128, 4 waves (2x2 of 64x64), BK=32, LDS chunk-major [q][row] (2-way free).
__global__ __launch_bounds__(256) void gemm1_mfma(const u16* __restrict__ xb,
                                                  const u16* __restrict__ Wt,
                                                  u16* __restrict__ y1) {
    __shared__ u16 lA[4096];  // [q 0..3][r 0..127] x 8 bf16
    __shared__ u16 lB[4096];
    const int t = threadIdx.x, wave = t >> 6, lane = t & 63;
    const int row0 = blockIdx.x * 128, col0 = blockIdx.y * 128;
    const int wr = wave >> 1, wc = wave & 1;
    const int q = lane >> 4, r16 = lane & 15;
    floatx4 acc[4][4] = {};
    for (int ks = 0; ks < 16; ks++) {
        const int ko = ks * 32;
#pragma unroll
        for (int s = 0; s < 2; s++) {
            const int i = wave * 2 + s, iq = i >> 1, r0v = (i & 1) * 64;
            int grow = row0 + r0v + lane; if (grow > NN - 1) grow = NN - 1;
            GLD16(xb + (size_t)grow * 512 + ko + iq * 8, &lA[(iq * 128 + r0v) * 8]);
            const int c = col0 + r0v + lane;
            GLD16(Wt + (size_t)c * 512 + ko + iq * 8, &lB[(iq * 128 + r0v) * 8]);
        }
        __builtin_amdgcn_s_waitcnt(0);
        __syncthreads();
        short8 a[4], b[4];
#pragma unroll
        for (int i = 0; i < 4; i++) a[i] = *(const short8*)&lA[(q * 128 + wr * 64 + i * 16 + r16) * 8];
#pragma unroll
        for (int j = 0; j < 4; j++) b[j] = *(const short8*)&lB[(q * 128 + wc * 64 + j * 16 + r16) * 8];
#pragma unroll
        for (int i = 0; i < 4; i++)
#pragma unroll
            for (int j = 0; j < 4; j++)
                acc[i][j] = __builtin_amdgcn_mfma_f32_16x16x32_bf16(a[i], b[j], acc[i][j], 0, 0, 0);
        __syncthreads();
    }
#pragma unroll
    for (int i = 0; i < 4; i++) {
        const int row = row0 + wr * 64 + i * 16 + q * 4;
#pragma unroll
        for (int j = 0; j < 4; j++) {
            const int col = col0 + wc * 64 + j * 16 + r16;
#pragma unroll
            for (int rg = 0; rg < 4; rg++) {
                if (row + rg < NN) y1[(size_t)(row + rg) * 256 + col] = f2bf(acc[i][j][rg]);
            }
        }
    }
}

// ---------------- GEMM2 (MFMA): h1 (y1 cols 128..256) @ Wt2^T -> y2[NN,64] fp32 -------
// tile 128x64, whole K=128 staged once, single barrier.
__global__ __launch_bounds__(256) void gemm2_mfma(const u16* __restrict__ y1,
                                                  const u16* __restrict__ Wt2,
                                                  float* __restrict__ y2) {
    __shared__ u16 lA[16384];  // [q 0..15][r 0..127] x 8
    __shared__ u16 lB[8192];   // [q 0..15][c 0..63] x 8
    const int t = threadIdx.x, wave = t >> 6, lane = t & 63;
    const int row0 = blockIdx.x * 128;
    const int r16 = lane & 15;
#pragma unroll
    for (int s = 0; s < 8; s++) {
        const int i = wave * 8 + s, iq = i >> 1, r0v = (i & 1) * 64;
        int grow = row0 + r0v + lane; if (grow > NN - 1) grow = NN - 1;
        GLD16(y1 + (size_t)grow * 256 + 128 + iq * 8, &lA[(iq * 128 + r0v) * 8]);
    }
#pragma unroll
    for (int s = 0; s < 4; s++) {
        const int qq = wave * 4 + s;
        GLD16(Wt2 + (size_t)lane * 128 + qq * 8, &lB[qq * 64 * 8]);
    }
    __builtin_amdgcn_s_waitcnt(0);
    __syncthreads();
    floatx4 acc[2][4] = {};
    for (int ks = 0; ks < 4; ks++) {
        const int qk = ks * 4 + (lane >> 4);
        short8 a[2], b[4];
#pragma unroll
        for (int i = 0; i < 2; i++) a[i] = *(const short8*)&lA[(qk * 128 + wave * 32 + i * 16 + r16) * 8];
#pragma unroll
        for (int j = 0; j < 4; j++) b[j] = *(const short8*)&lB[(qk * 64 + j * 16 + r16) * 8];
#pragma unroll
        for (int i = 0; i < 2; i++)
#pragma unroll
            for (int j = 0; j < 4; j++)
                acc[i][j] = __builtin_amdgcn_mfma_f32_16x16x32_bf16(a[i], b[j], acc[i][j], 0, 0, 0);
    }
#pragma unroll
    for (int i = 0; i < 2; i++) {
        const int row = row0 + wave * 32 + i * 16 + (lane >> 4) * 4;
#pragma unroll
        for (int j = 0; j < 4; j++) {
            const int col = j * 16 + r16;
#pragma unroll
            for (int rg = 0; rg < 4; rg++) {
                if (row + rg < NN) y2[(size_t)(row + rg) * 64 + col] = acc[i][j][rg];
            }
        }
    }
}

// ---------------- CSR build ----------------
__global__ void cnt_k(const int* __restrict__ dst, int* __restrict__ cnt) {
    const int e = blockIdx.x * 256 + threadIdx.x;
    if (e < NE) atomicAdd(&cnt[dst[e]], 1);
}

__global__ __launch_bounds__(1024) void scan_k(const int* __restrict__ cnt, int* __restrict__ rs) {
    __shared__ int part[1024];
    const int t = threadIdx.x;
    const int base = t * 49;
    int s = 0;
#pragma unroll 7
    for (int i = 0; i < 49; i++) {
        const int idx = base + i;
        if (idx < NN) s += cnt[idx];
    }
    part[t] = s;
    __syncthreads();
    for (int off = 1; off < 1024; off <<= 1) {
        const int v = (t >= off) ? part[t - off] : 0;
        __syncthreads();
        part[t] += v;
        __syncthreads();
    }
    int prefix = (t == 0) ? 0 : part[t - 1];
    for (int i = 0; i < 49; i++) {
        const int idx = base + i;
        if (idx < NN) {
            rs[idx] = prefix;
            prefix += cnt[idx];
        }
    }
    if (t == 1023) rs[NN] = prefix;
}

__global__ void place_k(const int* __restrict__ src, const int* __restrict__ dst,
                        const int* __restrict__ rs, int* __restrict__ cursor,
                        int* __restrict__ elist) {
    const int e = blockIdx.x * 256 + threadIdx.x;
    if (e < NE) {
        const int d = dst[e];
        const int p = atomicAdd(&cursor[d], 1);
        elist[rs[d] + p] = src[e];
    }
}

// ---------------- gather1: h1 = relu(mean y1l[nbr] + b + y1r) written into y1 cols 128..256
__global__ __launch_bounds__(256) void gather1_k(u16* y1, const int* __restrict__ rs,
                                                 const int* __restrict__ elist,
                                                 const float* __restrict__ b1l) {
    const int t = threadIdx.x;
    const int n = blockIdx.x * 4 + (t >> 6);
    const int lane = t & 63;
    const int s0 = rs[n], s1 = rs[n + 1];
    float a0 = 0.f, a1 = 0.f;
    for (int j = s0; j < s1; j++) {
        const int s = elist[j];
        const u32 v = *(const u32*)(y1 + (size_t)s * 256 + lane * 2);
        a0 += bflo(v);
        a1 += bfhi(v);
    }
    const float inv = 1.f / fmaxf((float)(s1 - s0), 1.f);
    u16* hp = y1 + (size_t)n * 256 + 128 + lane * 2;
    const u32 r = *(const u32*)hp;
    const float h0 = fmaxf(fmaf(a0, inv, b1l[lane * 2] + bflo(r)), 0.f);
    const float h1 = fmaxf(fmaf(a1, inv, b1l[lane * 2 + 1] + bfhi(r)), 0.f);
    *(u32*)hp = (u32)f2bf(h0) | ((u32)f2bf(h1) << 16);
}

// ---------------- gather2: h2[NN,32] fp32 = relu(mean y2l[nbr] + b + y2r) --------------
__global__ __launch_bounds__(256) void gather2_k(const float* __restrict__ y2,
                                                 const int* __restrict__ rs,
                                                 const int* __restrict__ elist,
                                                 const float* __restrict__ b2l,
                                                 float* __restrict__ h2) {
    const int t = threadIdx.x;
    const int n = blockIdx.x * 8 + (t >> 5);
    const int lane = t & 31;
    const int s0 = rs[n], s1 = rs[n + 1];
    float a = 0.f;
    for (int j = s0; j < s1; j++) {
        const int s = elist[j];
        a += y2[(size_t)s * 64 + lane];
    }
    const float inv = 1.f / fmaxf((float)(s1 - s0), 1.f);
    h2[(size_t)n * 32 + lane] = fmaxf(fmaf(a, inv, b2l[lane] + y2[(size_t)n * 64 + 32 + lane]), 0.f);
}

__device__ __forceinline__ float leaky(float v) { return v > 0.f ? v : 0.1f * v; }

// ---------------- pool + MLP head, one block per graph ----------------
__global__ __launch_bounds__(256) void poolmlp_k(const float* __restrict__ h2,
                                                 const int* __restrict__ batch,
                                                 const float* __restrict__ Wl1, const float* __restrict__ bl1,
                                                 const float* __restrict__ Wl2, const float* __restrict__ bl2,
                                                 const float* __restrict__ Wd1, const float* __restrict__ bd1,
                                                 const float* __restrict__ Wd2, const float* __restrict__ bd2,
                                                 const float* __restrict__ Wd3, const float* __restrict__ bd3,
                                                 float* __restrict__ out) {
    __shared__ float red[256];
    __shared__ float bufA[32];
    __shared__ float bufB[32];
    const int g = blockIdx.x;
    const int t = threadIdx.x;
    int s, e;
    {
        int lo = 0, hi = NN;
        while (lo < hi) { const int m = (lo + hi) >> 1; if (batch[m] < g) lo = m + 1; else hi = m; }
        s = lo;
        lo = 0; hi = NN;
        while (lo < hi) { const int m = (lo + hi) >> 1; if (batch[m] < g + 1) lo = m + 1; else hi = m; }
        e = lo;
    }
    const int f = t & 31, grp = t >> 5;
    float acc = 0.f;
    for (int n = s + grp; n < e; n += 8) acc += h2[(size_t)n * 32 + f];
    red[t] = acc;
    __syncthreads();
    if (t < 32) {
        float sum = 0.f;
#pragma unroll
        for (int k = 0; k < 8; k++) sum += red[f + 32 * k];
        bufA[f] = sum / fmaxf((float)(e - s), 1.f);
    }
    __syncthreads();
    if (t < 32) {
        float sacc = bl1[t];
#pragma unroll
        for (int k = 0; k < 32; k++) sacc = fmaf(bufA[k], Wl1[k * 32 + t], sacc);
        bufB[t] = fmaxf(sacc, 0.f);
    }
    __syncthreads();
    if (t < 16) {
        float sacc = bl2[t];
#pragma unroll
        for (int k = 0; k < 32; k++) sacc = fmaf(bufB[k], Wl2[k * 16 + t], sacc);
        const float ev = leaky(sacc);
        bufA[t] = ev;
        out[g * 16 + t] = ev;
    }
    __syncthreads();
    if (t < 32) {
        float sacc = bd1[t];
#pragma unroll
        for (int k = 0; k < 16; k++) sacc = fmaf(bufA[k], Wd1[k * 32 + t], sacc);
        bufB[t] = leaky(sacc);
    }
    __syncthreads();
    if (t < 32) {
        float sacc = bd2[t];
#pragma unroll
        for (int k = 0; k < 32; k++) sacc = fmaf(bufB[k], Wd2[k * 32 + t], sacc);
        bufA[t] = leaky(sacc);
    }
    __syncthreads();
    if (t < 50) {
        float sacc = bd3[t];
#pragma unroll
        for (int k = 0; k < 32; k++) sacc = fmaf(bufA[k], Wd3[k * 50 + t], sacc);
        out[1024 + g * 50 + t] = sacc;
    }
}

extern "C" void kernel_launch(void* const* d_in, const int* in_sizes, int n_in,
                              void* d_out, int out_size, void* d_ws, size_t ws_size,
                              hipStream_t stream) {
    const float* x = (const float*)d_in[0];
    const int* ei = (const int*)d_in[1];
    const int* src = ei;
    const int* dst = ei + NE;
    const int* batch = (const int*)d_in[2];
    const float* W1l = (const float*)d_in[3];
    const float* b1l = (const float*)d_in[4];
    const float* W1r = (const float*)d_in[5];
    const float* W2l = (const float*)d_in[6];
    const float* b2l = (const float*)d_in[7];
    const float* W2r = (const float*)d_in[8];
    const float* Wl1 = (const float*)d_in[9];
    const float* bl1 = (const float*)d_in[10];
    const float* Wl2 = (const float*)d_in[11];
    const float* bl2 = (const float*)d_in[12];
    const float* Wd1 = (const float*)d_in[13];
    const float* bd1 = (const float*)d_in[14];
    const float* Wd2 = (const float*)d_in[15];
    const float* bd2 = (const float*)d_in[16];
    const float* Wd3 = (const float*)d_in[17];
    const float* bd3 = (const float*)d_in[18];

    char* W = (char*)d_ws;
    // layout (bytes):
    u16* xb = (u16*)W;                         // [0, 51.2M)  bf16 x
    float* y2 = (float*)W;                     // aliases xb after gemm1 (12.8M)
    float* h2 = (float*)(W + 12800000);        // 6.4M
    u16* y1 = (u16*)(W + 51200000);            // 25.6M  [NN,256] bf16; cols 128..256 become h1
    u16* Wt1 = (u16*)(W + 76800000);           // 262144
    u16* Wt2 = (u16*)(W + 77062144);           // 16384
    int* rs = (int*)(W + 77078528);            // NN+1
    int* cursor = (int*)(W + 77278532);        // NN
    int* elist = (int*)(W + 77478532);         // NE

    // --- CSR build ---
    hipMemsetAsync(cursor, 0, (size_t)NN * 4, stream);
    cnt_k<<<(NE + 255) / 256, 256, 0, stream>>>(dst, cursor);
    scan_k<<<1, 1024, 0, stream>>>(cursor, rs);
    hipMemsetAsync(cursor, 0, (size_t)NN * 4, stream);
    place_k<<<(NE + 255) / 256, 256, 0, stream>>>(src, dst, rs, cursor, elist);

    // --- prep: cast + weight packing ---
    cast_k<<<12500, 256, 0, stream>>>(x, xb);
    prepw1_k<<<512, 256, 0, stream>>>(W1l, W1r, Wt1);
    prepw2_k<<<32, 256, 0, stream>>>(W2l, W2r, Wt2);

    // --- layer 1 ---
    gemm1_mfma<<<dim3(391, 2), 256, 0, stream>>>(xb, Wt1, y1);
    gather1_k<<<12500, 256, 0, stream>>>(y1, rs, elist, b1l);

    // --- layer 2 (y2/h2 alias dead xb region) ---
    gemm2_mfma<<<391, 256, 0, stream>>>(y1, Wt2, y2);
    gather2_k<<<6250, 256, 0, stream>>>(y2, rs, elist, b2l, h2);

    // --- pool + MLP head ---
    poolmlp_k<<<NG, 256, 0, stream>>>(h2, batch, Wl1, bl1, Wl2, bl2,
                                      Wd1, bd1, Wd2, bd2, Wd3, bd3, (float*)d_out);
}

// Round 4
// 407.218 us; speedup vs baseline: 4.2239x; 1.2187x over previous
//
#include <hip/hip_runtime.h>

#define NN 50000
#define NE 400000
#define NG 64
#define SCAN_B 196  // ceil(NN/256)

typedef unsigned short u16;
typedef unsigned int u32;
typedef short short8 __attribute__((ext_vector_type(8)));
typedef float floatx4 __attribute__((ext_vector_type(4)));

__device__ __forceinline__ u16 f2bf(float f) {  // RNE
    union { float f; u32 u; } v; v.f = f;
    return (u16)((v.u + 0x7fff + ((v.u >> 16) & 1)) >> 16);
}
__device__ __forceinline__ float bflo(u32 p) { union { u32 u; float f; } v; v.u = p << 16; return v.f; }
__device__ __forceinline__ float bfhi(u32 p) { union { u32 u; float f; } v; v.u = p & 0xffff0000u; return v.f; }

#define GLD16(g, l) __builtin_amdgcn_global_load_lds( \
    (const __attribute__((address_space(1))) void*)(g), \
    (__attribute__((address_space(3))) void*)(l), 16, 0, 0)

// ---------------- cast x (fp32) -> xb (bf16), 8 elems/thread ----------------
__global__ __launch_bounds__(256) void cast_k(const float* __restrict__ x, u16* __restrict__ xb) {
    const int gid = blockIdx.x * 256 + threadIdx.x;  // 3.2M threads
    const float4* xv = (const float4*)x;
    const float4 a = xv[gid * 2], b = xv[gid * 2 + 1];
    u32 o[4];
    o[0] = f2bf(a.x) | ((u32)f2bf(a.y) << 16);
    o[1] = f2bf(a.z) | ((u32)f2bf(a.w) << 16);
    o[2] = f2bf(b.x) | ((u32)f2bf(b.y) << 16);
    o[3] = f2bf(b.z) | ((u32)f2bf(b.w) << 16);
    ((uint4*)xb)[gid] = *(const uint4*)o;
}

// ---------------- pack W1l|W1r -> Wt1[256][512], W2l|W2r -> Wt2[64][128] (merged) ------
__global__ __launch_bounds__(256) void prepw_k(const float* __restrict__ W1l,
                                               const float* __restrict__ W1r,
                                               const float* __restrict__ W2l,
                                               const float* __restrict__ W2r,
                                               u16* __restrict__ Wt1,
                                               u16* __restrict__ Wt2) {
    const int gid = blockIdx.x * 256 + threadIdx.x;  // 139264 total
    if (gid < 131072) {
        const int c = gid >> 9, k = gid & 511;
        const float v = (c < 128) ? W1l[k * 128 + c] : W1r[k * 128 + (c - 128)];
        Wt1[gid] = f2bf(v);
    } else {
        const int g2 = gid - 131072;
        const int c = g2 >> 7, k = g2 & 127;
        const float v = (c < 32) ? W2l[k * 32 + c] : W2r[k * 32 + (c - 32)];
        Wt2[g2] = f2bf(v);
    }
}

// ---------------- GEMM1 (MFMA): xb[NN,512] @ Wt1^T -> y1[NN,256] bf16 ----------------
__global__ __launch_bounds__(256) void gemm1_mfma(const u16* __restrict__ xb,
                                                  const u16* __restrict__ Wt,
                                                  u16* __restrict__ y1) {
    __shared__ u16 lA[4096];  // [q 0..3][r 0..127] x 8 bf16
    __shared__ u16 lB[4096];
    const int t = threadIdx.x, wave = t >> 6, lane = t & 63;
    const int row0 = blockIdx.x * 128, col0 = blockIdx.y * 128;
    const int wr = wave >> 1, wc = wave & 1;
    const int q = lane >> 4, r16 = lane & 15;
    floatx4 acc[4][4] = {};
    for (int ks = 0; ks < 16; ks++) {
        const int ko = ks * 32;
#pragma unroll
        for (int s = 0; s < 2; s++) {
            const int i = wave * 2 + s, iq = i >> 1, r0v = (i & 1) * 64;
            int grow = row0 + r0v + lane; if (grow > NN - 1) grow = NN - 1;
            GLD16(xb + (size_t)grow * 512 + ko + iq * 8, &lA[(iq * 128 + r0v) * 8]);
            const int c = col0 + r0v + lane;
            GLD16(Wt + (size_t)c * 512 + ko + iq * 8, &lB[(iq * 128 + r0v) * 8]);
        }
        __builtin_amdgcn_s_waitcnt(0);
        __syncthreads();
        short8 a[4], b[4];
#pragma unroll
        for (int i = 0; i < 4; i++) a[i] = *(const short8*)&lA[(q * 128 + wr * 64 + i * 16 + r16) * 8];
#pragma unroll
        for (int j = 0; j < 4; j++) b[j] = *(const short8*)&lB[(q * 128 + wc * 64 + j * 16 + r16) * 8];
#pragma unroll
        for (int i = 0; i < 4; i++)
#pragma unroll
            for (int j = 0; j < 4; j++)
                acc[i][j] = __builtin_amdgcn_mfma_f32_16x16x32_bf16(a[i], b[j], acc[i][j], 0, 0, 0);
        __syncthreads();
    }
#pragma unroll
    for (int i = 0; i < 4; i++) {
        const int row = row0 + wr * 64 + i * 16 + q * 4;
#pragma unroll
        for (int j = 0; j < 4; j++) {
            const int col = col0 + wc * 64 + j * 16 + r16;
#pragma unroll
            for (int rg = 0; rg < 4; rg++) {
                if (row + rg < NN) y1[(size_t)(row + rg) * 256 + col] = f2bf(acc[i][j][rg]);
            }
        }
    }
}

// ---------------- GEMM2 (MFMA): h1 (y1 cols 128..256) @ Wt2^T -> y2[NN,64] fp32 -------
__global__ __launch_bounds__(256) void gemm2_mfma(const u16* __restrict__ y1,
                                                  const u16* __restrict__ Wt2,
                                                  float* __restrict__ y2) {
    __shared__ u16 lA[16384];  // [q 0..15][r 0..127] x 8
    __shared__ u16 lB[8192];   // [q 0..15][c 0..63] x 8
    const int t = threadIdx.x, wave = t >> 6, lane = t & 63;
    const int row0 = blockIdx.x * 128;
    const int r16 = lane & 15;
#pragma unroll
    for (int s = 0; s < 8; s++) {
        const int i = wave * 8 + s, iq = i >> 1, r0v = (i & 1) * 64;
        int grow = row0 + r0v + lane; if (grow > NN - 1) grow = NN - 1;
        GLD16(y1 + (size_t)grow * 256 + 128 + iq * 8, &lA[(iq * 128 + r0v) * 8]);
    }
#pragma unroll
    for (int s = 0; s < 4; s++) {
        const int qq = wave * 4 + s;
        GLD16(Wt2 + (size_t)lane * 128 + qq * 8, &lB[qq * 64 * 8]);
    }
    __builtin_amdgcn_s_waitcnt(0);
    __syncthreads();
    floatx4 acc[2][4] = {};
    for (int ks = 0; ks < 4; ks++) {
        const int qk = ks * 4 + (lane >> 4);
        short8 a[2], b[4];
#pragma unroll
        for (int i = 0; i < 2; i++) a[i] = *(const short8*)&lA[(qk * 128 + wave * 32 + i * 16 + r16) * 8];
#pragma unroll
        for (int j = 0; j < 4; j++) b[j] = *(const short8*)&lB[(qk * 64 + j * 16 + r16) * 8];
#pragma unroll
        for (int i = 0; i < 2; i++)
#pragma unroll
            for (int j = 0; j < 4; j++)
                acc[i][j] = __builtin_amdgcn_mfma_f32_16x16x32_bf16(a[i], b[j], acc[i][j], 0, 0, 0);
    }
#pragma unroll
    for (int i = 0; i < 2; i++) {
        const int row = row0 + wave * 32 + i * 16 + (lane >> 4) * 4;
#pragma unroll
        for (int j = 0; j < 4; j++) {
            const int col = j * 16 + r16;
#pragma unroll
            for (int rg = 0; rg < 4; rg++) {
                if (row + rg < NN) y2[(size_t)(row + rg) * 64 + col] = acc[i][j][rg];
            }
        }
    }
}

// ---------------- CSR build ----------------
__global__ void cnt_k(const int* __restrict__ dst, int* __restrict__ cnt) {
    const int e = blockIdx.x * 256 + threadIdx.x;
    if (e < NE) atomicAdd(&cnt[dst[e]], 1);
}

// phase 1: per-block inclusive scan of 256-chunk; local exclusive to rs; block total to bsum
__global__ __launch_bounds__(256) void scan1_k(const int* __restrict__ cnt,
                                               int* __restrict__ rs, int* __restrict__ bsum) {
    __shared__ int sm[256];
    const int t = threadIdx.x, b = blockIdx.x;
    const int idx = b * 256 + t;
    const int v = (idx < NN) ? cnt[idx] : 0;
    sm[t] = v;
    __syncthreads();
#pragma unroll
    for (int off = 1; off < 256; off <<= 1) {
        const int y = (t >= off) ? sm[t - off] : 0;
        __syncthreads();
        sm[t] += y;
        __syncthreads();
    }
    if (idx < NN) rs[idx] = sm[t] - v;
    if (t == 255) bsum[b] = sm[255];
}

// phase 2: exclusive scan of bsum[SCAN_B] in one block; total -> rs[NN]
__global__ __launch_bounds__(256) void scan2_k(const int* __restrict__ bsum,
                                               int* __restrict__ bpre, int* __restrict__ rs) {
    __shared__ int sm[256];
    const int t = threadIdx.x;
    const int v = (t < SCAN_B) ? bsum[t] : 0;
    sm[t] = v;
    __syncthreads();
#pragma unroll
    for (int off = 1; off < 256; off <<= 1) {
        const int y = (t >= off) ? sm[t - off] : 0;
        __syncthreads();
        sm[t] += y;
        __syncthreads();
    }
    if (t < SCAN_B) bpre[t] = sm[t] - v;
    if (t == 255) rs[NN] = sm[255];
}

// phase 3: add block prefix; zero cursor for place_k (saves a memset)
__global__ __launch_bounds__(256) void scan3_k(int* __restrict__ rs, const int* __restrict__ bpre,
                                               int* __restrict__ cursor) {
    const int idx = blockIdx.x * 256 + threadIdx.x;
    if (idx < NN) {
        rs[idx] += bpre[blockIdx.x];
        cursor[idx] = 0;
    }
}

__global__ void place_k(const int* __restrict__ src, const int* __restrict__ dst,
                        const int* __restrict__ rs, int* __restrict__ cursor,
                        int* __restrict__ elist) {
    const int e = blockIdx.x * 256 + threadIdx.x;
    if (e < NE) {
        const int d = dst[e];
        const int p = atomicAdd(&cursor[d], 1);
        elist[rs[d] + p] = src[e];
    }
}

// ---------------- gather1: h1 = relu(mean y1l[nbr] + b + y1r) into y1 cols 128..256 ----
__global__ __launch_bounds__(256) void gather1_k(u16* y1, const int* __restrict__ rs,
                                                 const int* __restrict__ elist,
                                                 const float* __restrict__ b1l) {
    const int t = threadIdx.x;
    const int n = blockIdx.x * 4 + (t >> 6);
    const int lane = t & 63;
    const int s0 = rs[n], s1 = rs[n + 1];
    float a0 = 0.f, a1 = 0.f;
    for (int j = s0; j < s1; j++) {
        const int s = elist[j];
        const u32 v = *(const u32*)(y1 + (size_t)s * 256 + lane * 2);
        a0 += bflo(v);
        a1 += bfhi(v);
    }
    const float inv = 1.f / fmaxf((float)(s1 - s0), 1.f);
    u16* hp = y1 + (size_t)n * 256 + 128 + lane * 2;
    const u32 r = *(const u32*)hp;
    const float h0 = fmaxf(fmaf(a0, inv, b1l[lane * 2] + bflo(r)), 0.f);
    const float h1 = fmaxf(fmaf(a1, inv, b1l[lane * 2 + 1] + bfhi(r)), 0.f);
    *(u32*)hp = (u32)f2bf(h0) | ((u32)f2bf(h1) << 16);
}

// ---------------- gather2: h2[NN,32] fp32 = relu(mean y2l[nbr] + b + y2r) --------------
__global__ __launch_bounds__(256) void gather2_k(const float* __restrict__ y2,
                                                 const int* __restrict__ rs,
                                                 const int* __restrict__ elist,
                                                 const float* __restrict__ b2l,
                                                 float* __restrict__ h2) {
    const int t = threadIdx.x;
    const int n = blockIdx.x * 8 + (t >> 5);
    const int lane = t & 31;
    const int s0 = rs[n], s1 = rs[n + 1];
    float a = 0.f;
    for (int j = s0; j < s1; j++) {
        const int s = elist[j];
        a += y2[(size_t)s * 64 + lane];
    }
    const float inv = 1.f / fmaxf((float)(s1 - s0), 1.f);
    h2[(size_t)n * 32 + lane] = fmaxf(fmaf(a, inv, b2l[lane] + y2[(size_t)n * 64 + 32 + lane]), 0.f);
}

__device__ __forceinline__ float leaky(float v) { return v > 0.f ? v : 0.1f * v; }

// ---------------- pool + MLP head, one block per graph ----------------
__global__ __launch_bounds__(256) void poolmlp_k(const float* __restrict__ h2,
                                                 const int* __restrict__ batch,
                                                 const float* __restrict__ Wl1, const float* __restrict__ bl1,
                                                 const float* __restrict__ Wl2, const float* __restrict__ bl2,
                                                 const float* __restrict__ Wd1, const float* __restrict__ bd1,
                                                 const float* __restrict__ Wd2, const float* __restrict__ bd2,
                                                 const float* __restrict__ Wd3, const float* __restrict__ bd3,
                                                 float* __restrict__ out) {
    __shared__ float red[256];
    __shared__ float bufA[32];
    __shared__ float bufB[32];
    const int g = blockIdx.x;
    const int t = threadIdx.x;
    int s, e;
    {
        int lo = 0, hi = NN;
        while (lo < hi) { const int m = (lo + hi) >> 1; if (batch[m] < g) lo = m + 1; else hi = m; }
        s = lo;
        lo = 0; hi = NN;
        while (lo < hi) { const int m = (lo + hi) >> 1; if (batch[m] < g + 1) lo = m + 1; else hi = m; }
        e = lo;
    }
    const int f = t & 31, grp = t >> 5;
    float acc = 0.f;
    for (int n = s + grp; n < e; n += 8) acc += h2[(size_t)n * 32 + f];
    red[t] = acc;
    __syncthreads();
    if (t < 32) {
        float sum = 0.f;
#pragma unroll
        for (int k = 0; k < 8; k++) sum += red[f + 32 * k];
        bufA[f] = sum / fmaxf((float)(e - s), 1.f);
    }
    __syncthreads();
    if (t < 32) {
        float sacc = bl1[t];
#pragma unroll
        for (int k = 0; k < 32; k++) sacc = fmaf(bufA[k], Wl1[k * 32 + t], sacc);
        bufB[t] = fmaxf(sacc, 0.f);
    }
    __syncthreads();
    if (t < 16) {
        float sacc = bl2[t];
#pragma unroll
        for (int k = 0; k < 32; k++) sacc = fmaf(bufB[k], Wl2[k * 16 + t], sacc);
        const float ev = leaky(sacc);
        bufA[t] = ev;
        out[g * 16 + t] = ev;
    }
    __syncthreads();
    if (t < 32) {
        float sacc = bd1[t];
#pragma unroll
        for (int k = 0; k < 16; k++) sacc = fmaf(bufA[k], Wd1[k * 32 + t], sacc);
        bufB[t] = leaky(sacc);
    }
    __syncthreads();
    if (t < 32) {
        float sacc = bd2[t];
#pragma unroll
        for (int k = 0; k < 32; k++) sacc = fmaf(bufB[k], Wd2[k * 32 + t], sacc);
        bufA[t] = leaky(sacc);
    }
    __syncthreads();
    if (t < 50) {
        float sacc = bd3[t];
#pragma unroll
        for (int k = 0; k < 32; k++) sacc = fmaf(bufA[k], Wd3[k * 50 + t], sacc);
        out[1024 + g * 50 + t] = sacc;
    }
}

extern "C" void kernel_launch(void* const* d_in, const int* in_sizes, int n_in,
                              void* d_out, int out_size, void* d_ws, size_t ws_size,
                              hipStream_t stream) {
    const float* x = (const float*)d_in[0];
    const int* ei = (const int*)d_in[1];
    const int* src = ei;
    const int* dst = ei + NE;
    const int* batch = (const int*)d_in[2];
    const float* W1l = (const float*)d_in[3];
    const float* b1l = (const float*)d_in[4];
    const float* W1r = (const float*)d_in[5];
    const float* W2l = (const float*)d_in[6];
    const float* b2l = (const float*)d_in[7];
    const float* W2r = (const float*)d_in[8];
    const float* Wl1 = (const float*)d_in[9];
    const float* bl1 = (const float*)d_in[10];
    const float* Wl2 = (const float*)d_in[11];
    const float* bl2 = (const float*)d_in[12];
    const float* Wd1 = (const float*)d_in[13];
    const float* bd1 = (const float*)d_in[14];
    const float* Wd2 = (const float*)d_in[15];
    const float* bd2 = (const float*)d_in[16];
    const float* Wd3 = (const float*)d_in[17];
    const float* bd3 = (const float*)d_in[18];

    char* W = (char*)d_ws;
    u16* xb = (u16*)W;                         // [0, 51.2M)  bf16 x
    float* y2 = (float*)W;                     // aliases xb after gemm1 (12.8M)
    float* h2 = (float*)(W + 12800000);        // 6.4M
    u16* y1 = (u16*)(W + 51200000);            // 25.6M  [NN,256] bf16; cols 128..256 become h1
    u16* Wt1 = (u16*)(W + 76800000);           // 262144
    u16* Wt2 = (u16*)(W + 77062144);           // 16384
    int* rs = (int*)(W + 77078528);            // NN+1
    int* cursor = (int*)(W + 77278532);        // NN
    int* elist = (int*)(W + 77478532);         // NE
    int* bsum = (int*)(W + 79078532);          // SCAN_B
    int* bpre = (int*)(W + 79079316);          // SCAN_B

    // --- CSR build ---
    hipMemsetAsync(cursor, 0, (size_t)NN * 4, stream);
    cnt_k<<<(NE + 255) / 256, 256, 0, stream>>>(dst, cursor);
    scan1_k<<<SCAN_B, 256, 0, stream>>>(cursor, rs, bsum);
    scan2_k<<<1, 256, 0, stream>>>(bsum, bpre, rs);
    scan3_k<<<SCAN_B, 256, 0, stream>>>(rs, bpre, cursor);  // also zeros cursor
    place_k<<<(NE + 255) / 256, 256, 0, stream>>>(src, dst, rs, cursor, elist);

    // --- prep: cast + weight packing ---
    cast_k<<<12500, 256, 0, stream>>>(x, xb);
    prepw_k<<<544, 256, 0, stream>>>(W1l, W1r, W2l, W2r, Wt1, Wt2);

    // --- layer 1 ---
    gemm1_mfma<<<dim3(391, 2), 256, 0, stream>>>(xb, Wt1, y1);
    gather1_k<<<12500, 256, 0, stream>>>(y1, rs, elist, b1l);

    // --- layer 2 (y2/h2 alias dead xb region) ---
    gemm2_mfma<<<391, 256, 0, stream>>>(y1, Wt2, y2);
    gather2_k<<<6250, 256, 0, stream>>>(y2, rs, elist, b2l, h2);

    // --- pool + MLP head ---
    poolmlp_k<<<NG, 256, 0, stream>>>(h2, batch, Wl1, bl1, Wl2, bl2,
                                      Wd1, bd1, Wd2, bd2, Wd3, bd3, (float*)d_out);
}

// Round 5
// 393.712 us; speedup vs baseline: 4.3688x; 1.0343x over previous
//
#include <hip/hip_runtime.h>

#define NN 50000
#define NE 400000
#define NG 64
#define SCAN_B 196  // ceil(NN/256)

typedef unsigned short u16;
typedef unsigned int u32;
typedef short short8 __attribute__((ext_vector_type(8)));
typedef float floatx4 __attribute__((ext_vector_type(4)));

__device__ __forceinline__ u16 f2bf(float f) {  // RNE
    union { float f; u32 u; } v; v.f = f;
    return (u16)((v.u + 0x7fff + ((v.u >> 16) & 1)) >> 16);
}
__device__ __forceinline__ float bflo(u32 p) { union { u32 u; float f; } v; v.u = p << 16; return v.f; }
__device__ __forceinline__ float bfhi(u32 p) { union { u32 u; float f; } v; v.u = p & 0xffff0000u; return v.f; }

#define GLD16(g, l) __builtin_amdgcn_global_load_lds( \
    (const __attribute__((address_space(1))) void*)(g), \
    (__attribute__((address_space(3))) void*)(l), 16, 0, 0)

// ---------------- pack W1l|W1r -> Wt1[256][512], W2l|W2r -> Wt2[64][128] (merged) ------
__global__ __launch_bounds__(256) void prepw_k(const float* __restrict__ W1l,
                                               const float* __restrict__ W1r,
                                               const float* __restrict__ W2l,
                                               const float* __restrict__ W2r,
                                               u16* __restrict__ Wt1,
                                               u16* __restrict__ Wt2) {
    const int gid = blockIdx.x * 256 + threadIdx.x;  // 139264 total
    if (gid < 131072) {
        const int c = gid >> 9, k = gid & 511;
        const float v = (c < 128) ? W1l[k * 128 + c] : W1r[k * 128 + (c - 128)];
        Wt1[gid] = f2bf(v);
    } else {
        const int g2 = gid - 131072;
        const int c = g2 >> 7, k = g2 & 127;
        const float v = (c < 32) ? W2l[k * 32 + c] : W2r[k * 32 + (c - 32)];
        Wt2[g2] = f2bf(v);
    }
}

// ---------------- GEMM1 (MFMA, fused fp32->bf16 cast): x[NN,512] @ Wt1^T -> y1[NN,256] bf16
// tile 128x256, 4 waves (2x2 of 64x128), BK=32, LDS chunk-major [q][row] (2-way free).
__global__ __launch_bounds__(256) void gemm1_mfma(const float* __restrict__ x,
                                                  const u16* __restrict__ Wt,
                                                  u16* __restrict__ y1) {
    __shared__ u16 lA[4096];  // [q 0..3][r 0..127] x 8 bf16 (8 KB)
    __shared__ u16 lB[8192];  // [q 0..3][c 0..255] x 8 bf16 (16 KB)
    const int t = threadIdx.x, wave = t >> 6, lane = t & 63;
    const int row0 = blockIdx.x * 128;
    const int wr = wave >> 1, wc = wave & 1;
    const int q = lane >> 4, r16 = lane & 15;
    floatx4 acc[4][8] = {};
    for (int ks = 0; ks < 16; ks++) {
        const int ko = ks * 32;
        // B: wave w stages k-subchunk q=w for all 256 cols (4 col-blocks of 64)
#pragma unroll
        for (int s = 0; s < 4; s++) {
            const int col = s * 64 + lane;
            GLD16(Wt + (size_t)col * 512 + ko + wave * 8, &lB[(wave * 256 + s * 64) * 8]);
        }
        // A: load fp32 x, convert to bf16 in-register, ds_write chunk-major
#pragma unroll
        for (int i = 0; i < 4; i++) {
            const int v = i * 256 + t;  // 0..1023 covers 128 rows x 8 float4-slots
            const int row = v >> 3, kslot = v & 7;
            int grow = row0 + row; if (grow > NN - 1) grow = NN - 1;
            const float4 f = *(const float4*)(x + (size_t)grow * 512 + ko + kslot * 4);
            uint2 p;
            p.x = f2bf(f.x) | ((u32)f2bf(f.y) << 16);
            p.y = f2bf(f.z) | ((u32)f2bf(f.w) << 16);
            *(uint2*)&lA[((kslot >> 1) * 128 + row) * 8 + (kslot & 1) * 4] = p;
        }
        __builtin_amdgcn_s_waitcnt(0);
        __syncthreads();
        short8 a[4], b[8];
#pragma unroll
        for (int i = 0; i < 4; i++) a[i] = *(const short8*)&lA[(q * 128 + wr * 64 + i * 16 + r16) * 8];
#pragma unroll
        for (int j = 0; j < 8; j++) b[j] = *(const short8*)&lB[(q * 256 + wc * 128 + j * 16 + r16) * 8];
#pragma unroll
        for (int i = 0; i < 4; i++)
#pragma unroll
            for (int j = 0; j < 8; j++)
                acc[i][j] = __builtin_amdgcn_mfma_f32_16x16x32_bf16(a[i], b[j], acc[i][j], 0, 0, 0);
        __syncthreads();
    }
#pragma unroll
    for (int i = 0; i < 4; i++) {
        const int row = row0 + wr * 64 + i * 16 + q * 4;
#pragma unroll
        for (int j = 0; j < 8; j++) {
            const int col = wc * 128 + j * 16 + r16;
#pragma unroll
            for (int rg = 0; rg < 4; rg++) {
                if (row + rg < NN) y1[(size_t)(row + rg) * 256 + col] = f2bf(acc[i][j][rg]);
            }
        }
    }
}

// ---------------- GEMM2 (MFMA): h1 (y1 cols 128..256) @ Wt2^T -> y2[NN,64] fp32 -------
__global__ __launch_bounds__(256) void gemm2_mfma(const u16* __restrict__ y1,
                                                  const u16* __restrict__ Wt2,
                                                  float* __restrict__ y2) {
    __shared__ u16 lA[16384];  // [q 0..15][r 0..127] x 8
    __shared__ u16 lB[8192];   // [q 0..15][c 0..63] x 8
    const int t = threadIdx.x, wave = t >> 6, lane = t & 63;
    const int row0 = blockIdx.x * 128;
    const int r16 = lane & 15;
#pragma unroll
    for (int s = 0; s < 8; s++) {
        const int i = wave * 8 + s, iq = i >> 1, r0v = (i & 1) * 64;
        int grow = row0 + r0v + lane; if (grow > NN - 1) grow = NN - 1;
        GLD16(y1 + (size_t)grow * 256 + 128 + iq * 8, &lA[(iq * 128 + r0v) * 8]);
    }
#pragma unroll
    for (int s = 0; s < 4; s++) {
        const int qq = wave * 4 + s;
        GLD16(Wt2 + (size_t)lane * 128 + qq * 8, &lB[qq * 64 * 8]);
    }
    __builtin_amdgcn_s_waitcnt(0);
    __syncthreads();
    floatx4 acc[2][4] = {};
    for (int ks = 0; ks < 4; ks++) {
        const int qk = ks * 4 + (lane >> 4);
        short8 a[2], b[4];
#pragma unroll
        for (int i = 0; i < 2; i++) a[i] = *(const short8*)&lA[(qk * 128 + wave * 32 + i * 16 + r16) * 8];
#pragma unroll
        for (int j = 0; j < 4; j++) b[j] = *(const short8*)&lB[(qk * 64 + j * 16 + r16) * 8];
#pragma unroll
        for (int i = 0; i < 2; i++)
#pragma unroll
            for (int j = 0; j < 4; j++)
                acc[i][j] = __builtin_amdgcn_mfma_f32_16x16x32_bf16(a[i], b[j], acc[i][j], 0, 0, 0);
    }
#pragma unroll
    for (int i = 0; i < 2; i++) {
        const int row = row0 + wave * 32 + i * 16 + (lane >> 4) * 4;
#pragma unroll
        for (int j = 0; j < 4; j++) {
            const int col = j * 16 + r16;
#pragma unroll
            for (int rg = 0; rg < 4; rg++) {
                if (row + rg < NN) y2[(size_t)(row + rg) * 64 + col] = acc[i][j][rg];
            }
        }
    }
}

// ---------------- CSR build ----------------
__global__ void cnt_k(const int* __restrict__ dst, int* __restrict__ cnt) {
    const int e = blockIdx.x * 256 + threadIdx.x;
    if (e < NE) atomicAdd(&cnt[dst[e]], 1);
}

__global__ __launch_bounds__(256) void scan1_k(const int* __restrict__ cnt,
                                               int* __restrict__ rs, int* __restrict__ bsum) {
    __shared__ int sm[256];
    const int t = threadIdx.x, b = blockIdx.x;
    const int idx = b * 256 + t;
    const int v = (idx < NN) ? cnt[idx] : 0;
    sm[t] = v;
    __syncthreads();
#pragma unroll
    for (int off = 1; off < 256; off <<= 1) {
        const int y = (t >= off) ? sm[t - off] : 0;
        __syncthreads();
        sm[t] += y;
        __syncthreads();
    }
    if (idx < NN) rs[idx] = sm[t] - v;
    if (t == 255) bsum[b] = sm[255];
}

__global__ __launch_bounds__(256) void scan2_k(const int* __restrict__ bsum,
                                               int* __restrict__ bpre, int* __restrict__ rs) {
    __shared__ int sm[256];
    const int t = threadIdx.x;
    const int v = (t < SCAN_B) ? bsum[t] : 0;
    sm[t] = v;
    __syncthreads();
#pragma unroll
    for (int off = 1; off < 256; off <<= 1) {
        const int y = (t >= off) ? sm[t - off] : 0;
        __syncthreads();
        sm[t] += y;
        __syncthreads();
    }
    if (t < SCAN_B) bpre[t] = sm[t] - v;
    if (t == 255) rs[NN] = sm[255];
}

__global__ __launch_bounds__(256) void scan3_k(int* __restrict__ rs, const int* __restrict__ bpre,
                                               int* __restrict__ cursor) {
    const int idx = blockIdx.x * 256 + threadIdx.x;
    if (idx < NN) {
        rs[idx] += bpre[blockIdx.x];
        cursor[idx] = 0;
    }
}

__global__ void place_k(const int* __restrict__ src, const int* __restrict__ dst,
                        const int* __restrict__ rs, int* __restrict__ cursor,
                        int* __restrict__ elist) {
    const int e = blockIdx.x * 256 + threadIdx.x;
    if (e < NE) {
        const int d = dst[e];
        const int p = atomicAdd(&cursor[d], 1);
        elist[rs[d] + p] = src[e];
    }
}

// ---------------- gather1: h1 = relu(mean y1l[nbr] + b + y1r) into y1 cols 128..256 ----
__global__ __launch_bounds__(256) void gather1_k(u16* y1, const int* __restrict__ rs,
                                                 const int* __restrict__ elist,
                                                 const float* __restrict__ b1l) {
    const int t = threadIdx.x;
    const int n = blockIdx.x * 4 + (t >> 6);
    const int lane = t & 63;
    const int s0 = rs[n], s1 = rs[n + 1];
    float a0 = 0.f, a1 = 0.f;
    for (int j = s0; j < s1; j++) {
        const int s = elist[j];
        const u32 v = *(const u32*)(y1 + (size_t)s * 256 + lane * 2);
        a0 += bflo(v);
        a1 += bfhi(v);
    }
    const float inv = 1.f / fmaxf((float)(s1 - s0), 1.f);
    u16* hp = y1 + (size_t)n * 256 + 128 + lane * 2;
    const u32 r = *(const u32*)hp;
    const float h0 = fmaxf(fmaf(a0, inv, b1l[lane * 2] + bflo(r)), 0.f);
    const float h1 = fmaxf(fmaf(a1, inv, b1l[lane * 2 + 1] + bfhi(r)), 0.f);
    *(u32*)hp = (u32)f2bf(h0) | ((u32)f2bf(h1) << 16);
}

// ---------------- gather2: h2[NN,32] fp32 = relu(mean y2l[nbr] + b + y2r) --------------
__global__ __launch_bounds__(256) void gather2_k(const float* __restrict__ y2,
                                                 const int* __restrict__ rs,
                                                 const int* __restrict__ elist,
                                                 const float* __restrict__ b2l,
                                                 float* __restrict__ h2) {
    const int t = threadIdx.x;
    const int n = blockIdx.x * 8 + (t >> 5);
    const int lane = t & 31;
    const int s0 = rs[n], s1 = rs[n + 1];
    float a = 0.f;
    for (int j = s0; j < s1; j++) {
        const int s = elist[j];
        a += y2[(size_t)s * 64 + lane];
    }
    const float inv = 1.f / fmaxf((float)(s1 - s0), 1.f);
    h2[(size_t)n * 32 + lane] = fmaxf(fmaf(a, inv, b2l[lane] + y2[(size_t)n * 64 + 32 + lane]), 0.f);
}

__device__ __forceinline__ float leaky(float v) { return v > 0.f ? v : 0.1f * v; }

// ---------------- pool + MLP head, one block per graph ----------------
__global__ __launch_bounds__(256) void poolmlp_k(const float* __restrict__ h2,
                                                 const int* __restrict__ batch,
                                                 const float* __restrict__ Wl1, const float* __restrict__ bl1,
                                                 const float* __restrict__ Wl2, const float* __restrict__ bl2,
                                                 const float* __restrict__ Wd1, const float* __restrict__ bd1,
                                                 const float* __restrict__ Wd2, const float* __restrict__ bd2,
                                                 const float* __restrict__ Wd3, const float* __restrict__ bd3,
                                                 float* __restrict__ out) {
    __shared__ float red[256];
    __shared__ float bufA[32];
    __shared__ float bufB[32];
    const int g = blockIdx.x;
    const int t = threadIdx.x;
    int s, e;
    {
        int lo = 0, hi = NN;
        while (lo < hi) { const int m = (lo + hi) >> 1; if (batch[m] < g) lo = m + 1; else hi = m; }
        s = lo;
        lo = 0; hi = NN;
        while (lo < hi) { const int m = (lo + hi) >> 1; if (batch[m] < g + 1) lo = m + 1; else hi = m; }
        e = lo;
    }
    const int f = t & 31, grp = t >> 5;
    float acc = 0.f;
    for (int n = s + grp; n < e; n += 8) acc += h2[(size_t)n * 32 + f];
    red[t] = acc;
    __syncthreads();
    if (t < 32) {
        float sum = 0.f;
#pragma unroll
        for (int k = 0; k < 8; k++) sum += red[f + 32 * k];
        bufA[f] = sum / fmaxf((float)(e - s), 1.f);
    }
    __syncthreads();
    if (t < 32) {
        float sacc = bl1[t];
#pragma unroll
        for (int k = 0; k < 32; k++) sacc = fmaf(bufA[k], Wl1[k * 32 + t], sacc);
        bufB[t] = fmaxf(sacc, 0.f);
    }
    __syncthreads();
    if (t < 16) {
        float sacc = bl2[t];
#pragma unroll
        for (int k = 0; k < 32; k++) sacc = fmaf(bufB[k], Wl2[k * 16 + t], sacc);
        const float ev = leaky(sacc);
        bufA[t] = ev;
        out[g * 16 + t] = ev;
    }
    __syncthreads();
    if (t < 32) {
        float sacc = bd1[t];
#pragma unroll
        for (int k = 0; k < 16; k++) sacc = fmaf(bufA[k], Wd1[k * 32 + t], sacc);
        bufB[t] = leaky(sacc);
    }
    __syncthreads();
    if (t < 32) {
        float sacc = bd2[t];
#pragma unroll
        for (int k = 0; k < 32; k++) sacc = fmaf(bufB[k], Wd2[k * 32 + t], sacc);
        bufA[t] = leaky(sacc);
    }
    __syncthreads();
    if (t < 50) {
        float sacc = bd3[t];
#pragma unroll
        for (int k = 0; k < 32; k++) sacc = fmaf(bufA[k], Wd3[k * 50 + t], sacc);
        out[1024 + g * 50 + t] = sacc;
    }
}

extern "C" void kernel_launch(void* const* d_in, const int* in_sizes, int n_in,
                              void* d_out, int out_size, void* d_ws, size_t ws_size,
                              hipStream_t stream) {
    const float* x = (const float*)d_in[0];
    const int* ei = (const int*)d_in[1];
    const int* src = ei;
    const int* dst = ei + NE;
    const int* batch = (const int*)d_in[2];
    const float* W1l = (const float*)d_in[3];
    const float* b1l = (const float*)d_in[4];
    const float* W1r = (const float*)d_in[5];
    const float* W2l = (const float*)d_in[6];
    const float* b2l = (const float*)d_in[7];
    const float* W2r = (const float*)d_in[8];
    const float* Wl1 = (const float*)d_in[9];
    const float* bl1 = (const float*)d_in[10];
    const float* Wl2 = (const float*)d_in[11];
    const float* bl2 = (const float*)d_in[12];
    const float* Wd1 = (const float*)d_in[13];
    const float* bd1 = (const float*)d_in[14];
    const float* Wd2 = (const float*)d_in[15];
    const float* bd2 = (const float*)d_in[16];
    const float* Wd3 = (const float*)d_in[17];
    const float* bd3 = (const float*)d_in[18];

    char* W = (char*)d_ws;
    float* y2 = (float*)W;                     // 12.8M
    float* h2 = (float*)(W + 12800000);        // 6.4M
    u16* y1 = (u16*)(W + 51200000);            // 25.6M  [NN,256] bf16; cols 128..256 become h1
    u16* Wt1 = (u16*)(W + 76800000);           // 262144
    u16* Wt2 = (u16*)(W + 77062144);           // 16384
    int* rs = (int*)(W + 77078528);            // NN+1
    int* cursor = (int*)(W + 77278532);        // NN
    int* elist = (int*)(W + 77478532);         // NE
    int* bsum = (int*)(W + 79078532);          // SCAN_B
    int* bpre = (int*)(W + 79079316);          // SCAN_B

    // --- CSR build ---
    hipMemsetAsync(cursor, 0, (size_t)NN * 4, stream);
    cnt_k<<<(NE + 255) / 256, 256, 0, stream>>>(dst, cursor);
    scan1_k<<<SCAN_B, 256, 0, stream>>>(cursor, rs, bsum);
    scan2_k<<<1, 256, 0, stream>>>(bsum, bpre, rs);
    scan3_k<<<SCAN_B, 256, 0, stream>>>(rs, bpre, cursor);  // also zeros cursor
    place_k<<<(NE + 255) / 256, 256, 0, stream>>>(src, dst, rs, cursor, elist);

    // --- weight packing ---
    prepw_k<<<544, 256, 0, stream>>>(W1l, W1r, W2l, W2r, Wt1, Wt2);

    // --- layer 1 (cast fused into GEMM) ---
    gemm1_mfma<<<391, 256, 0, stream>>>(x, Wt1, y1);
    gather1_k<<<12500, 256, 0, stream>>>(y1, rs, elist, b1l);

    // --- layer 2 ---
    gemm2_mfma<<<391, 256, 0, stream>>>(y1, Wt2, y2);
    gather2_k<<<6250, 256, 0, stream>>>(y2, rs, elist, b2l, h2);

    // --- pool + MLP head ---
    poolmlp_k<<<NG, 256, 0, stream>>>(h2, batch, Wl1, bl1, Wl2, bl2,
                                      Wd1, bd1, Wd2, bd2, Wd3, bd3, (float*)d_out);
}

// Round 6
// 378.166 us; speedup vs baseline: 4.5484x; 1.0411x over previous
//
#include <hip/hip_runtime.h>

#define NN 50000
#define NE 400000
#define NG 64
#define SCAN_B 196  // ceil(NN/256)

typedef unsigned short u16;
typedef unsigned int u32;
typedef short short8 __attribute__((ext_vector_type(8)));
typedef float floatx4 __attribute__((ext_vector_type(4)));

__device__ __forceinline__ u16 f2bf(float f) {  // RNE
    union { float f; u32 u; } v; v.f = f;
    return (u16)((v.u + 0x7fff + ((v.u >> 16) & 1)) >> 16);
}
__device__ __forceinline__ float bflo(u32 p) { union { u32 u; float f; } v; v.u = p << 16; return v.f; }
__device__ __forceinline__ float bfhi(u32 p) { union { u32 u; float f; } v; v.u = p & 0xffff0000u; return v.f; }

#define GLD16(g, l) __builtin_amdgcn_global_load_lds( \
    (const __attribute__((address_space(1))) void*)(g), \
    (__attribute__((address_space(3))) void*)(l), 16, 0, 0)

// ---- pack weights into GEMM-ready chunk-contiguous layouts ----
// Wt1r[cb][ks][q][c][j]  (cb:2, ks:16, q:4, c:128, j:8), k=ks*32+q*8+j, col=cb*128+c
// Wt2r[q][c][j]          (q:16, c:64, j:8),              k=q*8+j,       col=c
__global__ __launch_bounds__(256) void prepw_k(const float* __restrict__ W1l,
                                               const float* __restrict__ W1r,
                                               const float* __restrict__ W2l,
                                               const float* __restrict__ W2r,
                                               u16* __restrict__ Wt1r,
                                               u16* __restrict__ Wt2r) {
    const int gid = blockIdx.x * 256 + threadIdx.x;  // 139264 total
    if (gid < 131072) {
        const int j = gid & 7, c = (gid >> 3) & 127, q = (gid >> 10) & 3;
        const int ks = (gid >> 12) & 15, cb = gid >> 16;
        const int k = ks * 32 + q * 8 + j;
        const int col = cb * 128 + c;
        const float v = (col < 128) ? W1l[k * 128 + col] : W1r[k * 128 + (col - 128)];
        Wt1r[gid] = f2bf(v);
    } else {
        const int g2 = gid - 131072;  // 8192
        const int j = g2 & 7, c = (g2 >> 3) & 63, q = g2 >> 9;
        const int k = q * 8 + j;
        const float v = (c < 32) ? W2l[k * 32 + c] : W2r[k * 32 + (c - 32)];
        Wt2r[g2] = f2bf(v);
    }
}

// ---------------- GEMM1 (MFMA, fused fp32->bf16 cast): x[NN,512] @ W^T -> y1[NN,256] bf16
// tile 128x128, grid (391,2), 4 waves (2x2 of 64x64), BK=32, LDS chunk-major [q][row].
__global__ __launch_bounds__(256) void gemm1_mfma(const float* __restrict__ x,
                                                  const u16* __restrict__ Wt,
                                                  u16* __restrict__ y1) {
    __shared__ u16 lA[4096];  // [q 0..3][r 0..127] x 8 (8 KB)
    __shared__ u16 lB[4096];  // [q 0..3][c 0..127] x 8 (8 KB)
    const int t = threadIdx.x, wave = t >> 6, lane = t & 63;
    const int row0 = blockIdx.x * 128, cb = blockIdx.y;
    const int wr = wave >> 1, wc = wave & 1;
    const int q4 = lane >> 4, r16 = lane & 15;
    floatx4 acc[4][4] = {};
    for (int ks = 0; ks < 16; ks++) {
        // B: wave w stages its q=w plane (128 cols), fully coalesced 2x1KB
        const u16* bsrc = Wt + ((size_t)(((cb * 16 + ks) * 4 + wave) * 128)) * 8;
        GLD16(bsrc + (size_t)lane * 8, &lB[(wave * 128) * 8]);
        GLD16(bsrc + (size_t)(64 + lane) * 8, &lB[(wave * 128 + 64) * 8]);
        // A: fp32 load + in-reg cast + ds_write_b128, item v=(row,q)
#pragma unroll
        for (int i = 0; i < 2; i++) {
            const int v = i * 256 + t;  // 0..511
            const int row = v >> 2, q = v & 3;
            int grow = row0 + row; if (grow > NN - 1) grow = NN - 1;
            const float* xp = x + (size_t)grow * 512 + ks * 32 + q * 8;
            const float4 f0 = *(const float4*)xp;
            const float4 f1 = *(const float4*)(xp + 4);
            uint4 p;
            p.x = f2bf(f0.x) | ((u32)f2bf(f0.y) << 16);
            p.y = f2bf(f0.z) | ((u32)f2bf(f0.w) << 16);
            p.z = f2bf(f1.x) | ((u32)f2bf(f1.y) << 16);
            p.w = f2bf(f1.z) | ((u32)f2bf(f1.w) << 16);
            *(uint4*)&lA[(q * 128 + row) * 8] = p;
        }
        __builtin_amdgcn_s_waitcnt(0);
        __syncthreads();
        short8 a[4], b[4];
#pragma unroll
        for (int i = 0; i < 4; i++) a[i] = *(const short8*)&lA[(q4 * 128 + wr * 64 + i * 16 + r16) * 8];
#pragma unroll
        for (int j = 0; j < 4; j++) b[j] = *(const short8*)&lB[(q4 * 128 + wc * 64 + j * 16 + r16) * 8];
#pragma unroll
        for (int i = 0; i < 4; i++)
#pragma unroll
            for (int j = 0; j < 4; j++)
                acc[i][j] = __builtin_amdgcn_mfma_f32_16x16x32_bf16(a[i], b[j], acc[i][j], 0, 0, 0);
        __syncthreads();
    }
#pragma unroll
    for (int i = 0; i < 4; i++) {
        const int row = row0 + wr * 64 + i * 16 + q4 * 4;
#pragma unroll
        for (int j = 0; j < 4; j++) {
            const int col = cb * 128 + wc * 64 + j * 16 + r16;
#pragma unroll
            for (int rg = 0; rg < 4; rg++) {
                if (row + rg < NN) y1[(size_t)(row + rg) * 256 + col] = f2bf(acc[i][j][rg]);
            }
        }
    }
}

// ---------------- GEMM2 (MFMA): h1 (y1 cols 128..256) @ Wt2r -> y2[NN,64] fp32 -------
__global__ __launch_bounds__(256) void gemm2_mfma(const u16* __restrict__ y1,
                                                  const u16* __restrict__ Wt2r,
                                                  float* __restrict__ y2) {
    __shared__ u16 lA[16384];  // [q 0..15][r 0..127] x 8
    __shared__ u16 lB[8192];   // [q 0..15][c 0..63] x 8
    const int t = threadIdx.x, wave = t >> 6, lane = t & 63;
    const int row0 = blockIdx.x * 128;
    const int r16 = lane & 15;
#pragma unroll
    for (int s = 0; s < 8; s++) {
        const int i = wave * 8 + s, iq = i >> 1, r0v = (i & 1) * 64;
        int grow = row0 + r0v + lane; if (grow > NN - 1) grow = NN - 1;
        GLD16(y1 + (size_t)grow * 256 + 128 + iq * 8, &lA[(iq * 128 + r0v) * 8]);
    }
#pragma unroll
    for (int s = 0; s < 4; s++) {
        const int qq = wave * 4 + s;
        GLD16(Wt2r + (size_t)(qq * 64) * 8 + (size_t)lane * 8, &lB[qq * 64 * 8]);
    }
    __builtin_amdgcn_s_waitcnt(0);
    __syncthreads();
    floatx4 acc[2][4] = {};
    for (int ks = 0; ks < 4; ks++) {
        const int qk = ks * 4 + (lane >> 4);
        short8 a[2], b[4];
#pragma unroll
        for (int i = 0; i < 2; i++) a[i] = *(const short8*)&lA[(qk * 128 + wave * 32 + i * 16 + r16) * 8];
#pragma unroll
        for (int j = 0; j < 4; j++) b[j] = *(const short8*)&lB[(qk * 64 + j * 16 + r16) * 8];
#pragma unroll
        for (int i = 0; i < 2; i++)
#pragma unroll
            for (int j = 0; j < 4; j++)
                acc[i][j] = __builtin_amdgcn_mfma_f32_16x16x32_bf16(a[i], b[j], acc[i][j], 0, 0, 0);
    }
#pragma unroll
    for (int i = 0; i < 2; i++) {
        const int row = row0 + wave * 32 + i * 16 + (lane >> 4) * 4;
#pragma unroll
        for (int j = 0; j < 4; j++) {
            const int col = j * 16 + r16;
#pragma unroll
            for (int rg = 0; rg < 4; rg++) {
                if (row + rg < NN) y2[(size_t)(row + rg) * 64 + col] = acc[i][j][rg];
            }
        }
    }
}

// ---------------- CSR build ----------------
__global__ void cnt_k(const int* __restrict__ dst, int* __restrict__ cnt) {
    const int e = blockIdx.x * 256 + threadIdx.x;
    if (e < NE) atomicAdd(&cnt[dst[e]], 1);
}

__global__ __launch_bounds__(256) void scan1_k(const int* __restrict__ cnt,
                                               int* __restrict__ rs, int* __restrict__ bsum) {
    __shared__ int sm[256];
    const int t = threadIdx.x, b = blockIdx.x;
    const int idx = b * 256 + t;
    const int v = (idx < NN) ? cnt[idx] : 0;
    sm[t] = v;
    __syncthreads();
#pragma unroll
    for (int off = 1; off < 256; off <<= 1) {
        const int y = (t >= off) ? sm[t - off] : 0;
        __syncthreads();
        sm[t] += y;
        __syncthreads();
    }
    if (idx < NN) rs[idx] = sm[t] - v;
    if (t == 255) bsum[b] = sm[255];
}

__global__ __launch_bounds__(256) void scan2_k(const int* __restrict__ bsum,
                                               int* __restrict__ bpre, int* __restrict__ rs) {
    __shared__ int sm[256];
    const int t = threadIdx.x;
    const int v = (t < SCAN_B) ? bsum[t] : 0;
    sm[t] = v;
    __syncthreads();
#pragma unroll
    for (int off = 1; off < 256; off <<= 1) {
        const int y = (t >= off) ? sm[t - off] : 0;
        __syncthreads();
        sm[t] += y;
        __syncthreads();
    }
    if (t < SCAN_B) bpre[t] = sm[t] - v;
    if (t == 255) rs[NN] = sm[255];
}

__global__ __launch_bounds__(256) void scan3_k(int* __restrict__ rs, const int* __restrict__ bpre,
                                               int* __restrict__ cursor) {
    const int idx = blockIdx.x * 256 + threadIdx.x;
    if (idx < NN) {
        rs[idx] += bpre[blockIdx.x];
        cursor[idx] = 0;
    }
}

__global__ void place_k(const int* __restrict__ src, const int* __restrict__ dst,
                        const int* __restrict__ rs, int* __restrict__ cursor,
                        int* __restrict__ elist) {
    const int e = blockIdx.x * 256 + threadIdx.x;
    if (e < NE) {
        const int d = dst[e];
        const int p = atomicAdd(&cursor[d], 1);
        elist[rs[d] + p] = src[e];
    }
}

// ---------------- gather1: h1 = relu(mean y1l[nbr] + b + y1r) into y1 cols 128..256 ----
__global__ __launch_bounds__(256) void gather1_k(u16* y1, const int* __restrict__ rs,
                                                 const int* __restrict__ elist,
                                                 const float* __restrict__ b1l) {
    const int t = threadIdx.x;
    const int n = blockIdx.x * 4 + (t >> 6);
    const int lane = t & 63;
    const int s0 = rs[n], s1 = rs[n + 1];
    float a0 = 0.f, a1 = 0.f;
    for (int j = s0; j < s1; j++) {
        const int s = elist[j];
        const u32 v = *(const u32*)(y1 + (size_t)s * 256 + lane * 2);
        a0 += bflo(v);
        a1 += bfhi(v);
    }
    const float inv = 1.f / fmaxf((float)(s1 - s0), 1.f);
    u16* hp = y1 + (size_t)n * 256 + 128 + lane * 2;
    const u32 r = *(const u32*)hp;
    const float h0 = fmaxf(fmaf(a0, inv, b1l[lane * 2] + bflo(r)), 0.f);
    const float h1 = fmaxf(fmaf(a1, inv, b1l[lane * 2 + 1] + bfhi(r)), 0.f);
    *(u32*)hp = (u32)f2bf(h0) | ((u32)f2bf(h1) << 16);
}

// ---------------- gather2: h2[NN,32] fp32 = relu(mean y2l[nbr] + b + y2r) --------------
__global__ __launch_bounds__(256) void gather2_k(const float* __restrict__ y2,
                                                 const int* __restrict__ rs,
                                                 const int* __restrict__ elist,
                                                 const float* __restrict__ b2l,
                                                 float* __restrict__ h2) {
    const int t = threadIdx.x;
    const int n = blockIdx.x * 8 + (t >> 5);
    const int lane = t & 31;
    const int s0 = rs[n], s1 = rs[n + 1];
    float a = 0.f;
    for (int j = s0; j < s1; j++) {
        const int s = elist[j];
        a += y2[(size_t)s * 64 + lane];
    }
    const float inv = 1.f / fmaxf((float)(s1 - s0), 1.f);
    h2[(size_t)n * 32 + lane] = fmaxf(fmaf(a, inv, b2l[lane] + y2[(size_t)n * 64 + 32 + lane]), 0.f);
}

__device__ __forceinline__ float leaky(float v) { return v > 0.f ? v : 0.1f * v; }

// ---------------- pool + MLP head, one block per graph ----------------
__global__ __launch_bounds__(256) void poolmlp_k(const float* __restrict__ h2,
                                                 const int* __restrict__ batch,
                                                 const float* __restrict__ Wl1, const float* __restrict__ bl1,
                                                 const float* __restrict__ Wl2, const float* __restrict__ bl2,
                                                 const float* __restrict__ Wd1, const float* __restrict__ bd1,
                                                 const float* __restrict__ Wd2, const float* __restrict__ bd2,
                                                 const float* __restrict__ Wd3, const float* __restrict__ bd3,
                                                 float* __restrict__ out) {
    __shared__ float red[256];
    __shared__ float bufA[32];
    __shared__ float bufB[32];
    const int g = blockIdx.x;
    const int t = threadIdx.x;
    int s, e;
    {
        int lo = 0, hi = NN;
        while (lo < hi) { const int m = (lo + hi) >> 1; if (batch[m] < g) lo = m + 1; else hi = m; }
        s = lo;
        lo = 0; hi = NN;
        while (lo < hi) { const int m = (lo + hi) >> 1; if (batch[m] < g + 1) lo = m + 1; else hi = m; }
        e = lo;
    }
    const int f = t & 31, grp = t >> 5;
    float acc = 0.f;
    for (int n = s + grp; n < e; n += 8) acc += h2[(size_t)n * 32 + f];
    red[t] = acc;
    __syncthreads();
    if (t < 32) {
        float sum = 0.f;
#pragma unroll
        for (int k = 0; k < 8; k++) sum += red[f + 32 * k];
        bufA[f] = sum / fmaxf((float)(e - s), 1.f);
    }
    __syncthreads();
    if (t < 32) {
        float sacc = bl1[t];
#pragma unroll
        for (int k = 0; k < 32; k++) sacc = fmaf(bufA[k], Wl1[k * 32 + t], sacc);
        bufB[t] = fmaxf(sacc, 0.f);
    }
    __syncthreads();
    if (t < 16) {
        float sacc = bl2[t];
#pragma unroll
        for (int k = 0; k < 32; k++) sacc = fmaf(bufB[k], Wl2[k * 16 + t], sacc);
        const float ev = leaky(sacc);
        bufA[t] = ev;
        out[g * 16 + t] = ev;
    }
    __syncthreads();
    if (t < 32) {
        float sacc = bd1[t];
#pragma unroll
        for (int k = 0; k < 16; k++) sacc = fmaf(bufA[k], Wd1[k * 32 + t], sacc);
        bufB[t] = leaky(sacc);
    }
    __syncthreads();
    if (t < 32) {
        float sacc = bd2[t];
#pragma unroll
        for (int k = 0; k < 32; k++) sacc = fmaf(bufB[k], Wd2[k * 32 + t], sacc);
        bufA[t] = leaky(sacc);
    }
    __syncthreads();
    if (t < 50) {
        float sacc = bd3[t];
#pragma unroll
        for (int k = 0; k < 32; k++) sacc = fmaf(bufA[k], Wd3[k * 50 + t], sacc);
        out[1024 + g * 50 + t] = sacc;
    }
}

extern "C" void kernel_launch(void* const* d_in, const int* in_sizes, int n_in,
                              void* d_out, int out_size, void* d_ws, size_t ws_size,
                              hipStream_t stream) {
    const float* x = (const float*)d_in[0];
    const int* ei = (const int*)d_in[1];
    const int* src = ei;
    const int* dst = ei + NE;
    const int* batch = (const int*)d_in[2];
    const float* W1l = (const float*)d_in[3];
    const float* b1l = (const float*)d_in[4];
    const float* W1r = (const float*)d_in[5];
    const float* W2l = (const float*)d_in[6];
    const float* b2l = (const float*)d_in[7];
    const float* W2r = (const float*)d_in[8];
    const float* Wl1 = (const float*)d_in[9];
    const float* bl1 = (const float*)d_in[10];
    const float* Wl2 = (const float*)d_in[11];
    const float* bl2 = (const float*)d_in[12];
    const float* Wd1 = (const float*)d_in[13];
    const float* bd1 = (const float*)d_in[14];
    const float* Wd2 = (const float*)d_in[15];
    const float* bd2 = (const float*)d_in[16];
    const float* Wd3 = (const float*)d_in[17];
    const float* bd3 = (const float*)d_in[18];

    char* W = (char*)d_ws;
    float* y2 = (float*)W;                     // 12.8M
    float* h2 = (float*)(W + 12800000);        // 6.4M
    u16* y1 = (u16*)(W + 51200000);            // 25.6M  [NN,256] bf16; cols 128..256 become h1
    u16* Wt1r = (u16*)(W + 76800000);          // 262144
    u16* Wt2r = (u16*)(W + 77062144);          // 16384
    int* rs = (int*)(W + 77078528);            // NN+1
    int* cursor = (int*)(W + 77278532);        // NN
    int* elist = (int*)(W + 77478532);         // NE
    int* bsum = (int*)(W + 79078532);          // SCAN_B
    int* bpre = (int*)(W + 79079316);          // SCAN_B

    // --- CSR build ---
    hipMemsetAsync(cursor, 0, (size_t)NN * 4, stream);
    cnt_k<<<(NE + 255) / 256, 256, 0, stream>>>(dst, cursor);
    scan1_k<<<SCAN_B, 256, 0, stream>>>(cursor, rs, bsum);
    scan2_k<<<1, 256, 0, stream>>>(bsum, bpre, rs);
    scan3_k<<<SCAN_B, 256, 0, stream>>>(rs, bpre, cursor);  // also zeros cursor
    place_k<<<(NE + 255) / 256, 256, 0, stream>>>(src, dst, rs, cursor, elist);

    // --- weight packing (GEMM-ready layouts) ---
    prepw_k<<<544, 256, 0, stream>>>(W1l, W1r, W2l, W2r, Wt1r, Wt2r);

    // --- layer 1 (cast fused into GEMM) ---
    gemm1_mfma<<<dim3(391, 2), 256, 0, stream>>>(x, Wt1r, y1);
    gather1_k<<<12500, 256, 0, stream>>>(y1, rs, elist, b1l);

    // --- layer 2 ---
    gemm2_mfma<<<391, 256, 0, stream>>>(y1, Wt2r, y2);
    gather2_k<<<6250, 256, 0, stream>>>(y2, rs, elist, b2l, h2);

    // --- pool + MLP head ---
    poolmlp_k<<<NG, 256, 0, stream>>>(h2, batch, Wl1, bl1, Wl2, bl2,
                                      Wd1, bd1, Wd2, bd2, Wd3, bd3, (float*)d_out);
}

// Round 7
// 377.262 us; speedup vs baseline: 4.5593x; 1.0024x over previous
//
#include <hip/hip_runtime.h>

#define NN 50000
#define NE 400000
#define NG 64
#define SCAN_B 196  // ceil(NN/256)

typedef unsigned short u16;
typedef unsigned int u32;
typedef short short8 __attribute__((ext_vector_type(8)));
typedef float floatx4 __attribute__((ext_vector_type(4)));

__device__ __forceinline__ u16 f2bf(float f) {  // RNE
    union { float f; u32 u; } v; v.f = f;
    return (u16)((v.u + 0x7fff + ((v.u >> 16) & 1)) >> 16);
}
__device__ __forceinline__ float bflo(u32 p) { union { u32 u; float f; } v; v.u = p << 16; return v.f; }
__device__ __forceinline__ float bfhi(u32 p) { union { u32 u; float f; } v; v.u = p & 0xffff0000u; return v.f; }

#define GLD16(g, l) __builtin_amdgcn_global_load_lds( \
    (const __attribute__((address_space(1))) void*)(g), \
    (__attribute__((address_space(3))) void*)(l), 16, 0, 0)

// ---- pack weights into GEMM-ready chunk-contiguous layouts ----
// Wt1r[cb][ks][q][c][j]  (cb:2, ks:16, q:4, c:128, j:8), k=ks*32+q*8+j, col=cb*128+c
// Wt2r[q][c][j]          (q:16, c:64, j:8),              k=q*8+j,       col=c
__global__ __launch_bounds__(256) void prepw_k(const float* __restrict__ W1l,
                                               const float* __restrict__ W1r,
                                               const float* __restrict__ W2l,
                                               const float* __restrict__ W2r,
                                               u16* __restrict__ Wt1r,
                                               u16* __restrict__ Wt2r) {
    const int gid = blockIdx.x * 256 + threadIdx.x;  // 139264 total
    if (gid < 131072) {
        const int j = gid & 7, c = (gid >> 3) & 127, q = (gid >> 10) & 3;
        const int ks = (gid >> 12) & 15, cb = gid >> 16;
        const int k = ks * 32 + q * 8 + j;
        const int col = cb * 128 + c;
        const float v = (col < 128) ? W1l[k * 128 + col] : W1r[k * 128 + (col - 128)];
        Wt1r[gid] = f2bf(v);
    } else {
        const int g2 = gid - 131072;  // 8192
        const int j = g2 & 7, c = (g2 >> 3) & 63, q = g2 >> 9;
        const int k = q * 8 + j;
        const float v = (c < 32) ? W2l[k * 32 + c] : W2r[k * 32 + (c - 32)];
        Wt2r[g2] = f2bf(v);
    }
}

// ---------------- GEMM1 (MFMA, fused cast, double-buffered pipeline) ----------------
// x[NN,512] @ W^T -> y1[NN,256] bf16. tile 128x128, grid (391,2), 4 waves (2x2 of 64x64),
// BK=32. Prefetch for ks+1 issued right after the barrier, hidden under ks's MFMAs.
__global__ __launch_bounds__(256) void gemm1_mfma(const float* __restrict__ x,
                                                  const u16* __restrict__ Wt,
                                                  u16* __restrict__ y1) {
    __shared__ u16 lA[2][4096];  // [q 0..3][r 0..127] x 8 (8 KB each)
    __shared__ u16 lB[2][4096];  // [q 0..3][c 0..127] x 8
    const int t = threadIdx.x, wave = t >> 6, lane = t & 63;
    const int row0 = blockIdx.x * 128, cb = blockIdx.y;
    const int wr = wave >> 1, wc = wave & 1;
    const int q4 = lane >> 4, r16 = lane & 15;

    // per-thread A items: v = i*256+t -> row=v>>2 (0..127), q=v&3
    int arow[2], aq[2];
    const float* xp0[2];
#pragma unroll
    for (int i = 0; i < 2; i++) {
        const int v = i * 256 + t;
        arow[i] = v >> 2; aq[i] = v & 3;
        int grow = row0 + arow[i]; if (grow > NN - 1) grow = NN - 1;
        xp0[i] = x + (size_t)grow * 512 + aq[i] * 8;
    }

    // prologue: stage ks=0
#pragma unroll
    for (int i = 0; i < 2; i++) {
        const float4 f0 = *(const float4*)xp0[i];
        const float4 f1 = *(const float4*)(xp0[i] + 4);
        uint4 p;
        p.x = f2bf(f0.x) | ((u32)f2bf(f0.y) << 16);
        p.y = f2bf(f0.z) | ((u32)f2bf(f0.w) << 16);
        p.z = f2bf(f1.x) | ((u32)f2bf(f1.y) << 16);
        p.w = f2bf(f1.z) | ((u32)f2bf(f1.w) << 16);
        *(uint4*)&lA[0][(aq[i] * 128 + arow[i]) * 8] = p;
    }
    {
        const u16* bsrc = Wt + ((size_t)(((cb * 16) * 4 + wave) * 128)) * 8;
        GLD16(bsrc + (size_t)lane * 8, &lB[0][(wave * 128) * 8]);
        GLD16(bsrc + (size_t)(64 + lane) * 8, &lB[0][(wave * 128 + 64) * 8]);
    }

    floatx4 acc[4][4] = {};
    for (int ks = 0; ks < 16; ks++) {
        const int p = ks & 1;
        __syncthreads();  // lA[p]/lB[p] ready; all reads of [p^1] retired
        float4 f[2][2];
        if (ks < 15) {
            // prefetch A (fp32 -> regs) and B (GLD16 -> lB[p^1]) for ks+1
#pragma unroll
            for (int i = 0; i < 2; i++) {
                const float* xp = xp0[i] + (ks + 1) * 32;
                f[i][0] = *(const float4*)xp;
                f[i][1] = *(const float4*)(xp + 4);
            }
            const u16* bsrc = Wt + ((size_t)(((cb * 16 + ks + 1) * 4 + wave) * 128)) * 8;
            GLD16(bsrc + (size_t)lane * 8, &lB[p ^ 1][(wave * 128) * 8]);
            GLD16(bsrc + (size_t)(64 + lane) * 8, &lB[p ^ 1][(wave * 128 + 64) * 8]);
        }
        short8 a[4], b[4];
#pragma unroll
        for (int i = 0; i < 4; i++) a[i] = *(const short8*)&lA[p][(q4 * 128 + wr * 64 + i * 16 + r16) * 8];
#pragma unroll
        for (int j = 0; j < 4; j++) b[j] = *(const short8*)&lB[p][(q4 * 128 + wc * 64 + j * 16 + r16) * 8];
#pragma unroll
        for (int i = 0; i < 4; i++)
#pragma unroll
            for (int j = 0; j < 4; j++)
                acc[i][j] = __builtin_amdgcn_mfma_f32_16x16x32_bf16(a[i], b[j], acc[i][j], 0, 0, 0);
        if (ks < 15) {
#pragma unroll
            for (int i = 0; i < 2; i++) {
                uint4 pk;
                pk.x = f2bf(f[i][0].x) | ((u32)f2bf(f[i][0].y) << 16);
                pk.y = f2bf(f[i][0].z) | ((u32)f2bf(f[i][0].w) << 16);
                pk.z = f2bf(f[i][1].x) | ((u32)f2bf(f[i][1].y) << 16);
                pk.w = f2bf(f[i][1].z) | ((u32)f2bf(f[i][1].w) << 16);
                *(uint4*)&lA[p ^ 1][(aq[i] * 128 + arow[i]) * 8] = pk;
            }
        }
    }
#pragma unroll
    for (int i = 0; i < 4; i++) {
        const int row = row0 + wr * 64 + i * 16 + q4 * 4;
#pragma unroll
        for (int j = 0; j < 4; j++) {
            const int col = cb * 128 + wc * 64 + j * 16 + r16;
#pragma unroll
            for (int rg = 0; rg < 4; rg++) {
                if (row + rg < NN) y1[(size_t)(row + rg) * 256 + col] = f2bf(acc[i][j][rg]);
            }
        }
    }
}

// ---------------- GEMM2 (MFMA): h1 (y1 cols 128..256) @ Wt2r -> y2[NN,64] fp32 -------
__global__ __launch_bounds__(256) void gemm2_mfma(const u16* __restrict__ y1,
                                                  const u16* __restrict__ Wt2r,
                                                  float* __restrict__ y2) {
    __shared__ u16 lA[16384];  // [q 0..15][r 0..127] x 8
    __shared__ u16 lB[8192];   // [q 0..15][c 0..63] x 8
    const int t = threadIdx.x, wave = t >> 6, lane = t & 63;
    const int row0 = blockIdx.x * 128;
    const int r16 = lane & 15;
#pragma unroll
    for (int s = 0; s < 8; s++) {
        const int i = wave * 8 + s, iq = i >> 1, r0v = (i & 1) * 64;
        int grow = row0 + r0v + lane; if (grow > NN - 1) grow = NN - 1;
        GLD16(y1 + (size_t)grow * 256 + 128 + iq * 8, &lA[(iq * 128 + r0v) * 8]);
    }
#pragma unroll
    for (int s = 0; s < 4; s++) {
        const int qq = wave * 4 + s;
        GLD16(Wt2r + (size_t)(qq * 64) * 8 + (size_t)lane * 8, &lB[qq * 64 * 8]);
    }
    __builtin_amdgcn_s_waitcnt(0);
    __syncthreads();
    floatx4 acc[2][4] = {};
    for (int ks = 0; ks < 4; ks++) {
        const int qk = ks * 4 + (lane >> 4);
        short8 a[2], b[4];
#pragma unroll
        for (int i = 0; i < 2; i++) a[i] = *(const short8*)&lA[(qk * 128 + wave * 32 + i * 16 + r16) * 8];
#pragma unroll
        for (int j = 0; j < 4; j++) b[j] = *(const short8*)&lB[(qk * 64 + j * 16 + r16) * 8];
#pragma unroll
        for (int i = 0; i < 2; i++)
#pragma unroll
            for (int j = 0; j < 4; j++)
                acc[i][j] = __builtin_amdgcn_mfma_f32_16x16x32_bf16(a[i], b[j], acc[i][j], 0, 0, 0);
    }
#pragma unroll
    for (int i = 0; i < 2; i++) {
        const int row = row0 + wave * 32 + i * 16 + (lane >> 4) * 4;
#pragma unroll
        for (int j = 0; j < 4; j++) {
            const int col = j * 16 + r16;
#pragma unroll
            for (int rg = 0; rg < 4; rg++) {
                if (row + rg < NN) y2[(size_t)(row + rg) * 64 + col] = acc[i][j][rg];
            }
        }
    }
}

// ---------------- CSR build ----------------
__global__ void cnt_k(const int* __restrict__ dst, int* __restrict__ cnt) {
    const int e = blockIdx.x * 256 + threadIdx.x;
    if (e < NE) atomicAdd(&cnt[dst[e]], 1);
}

__global__ __launch_bounds__(256) void scan1_k(const int* __restrict__ cnt,
                                               int* __restrict__ rs, int* __restrict__ bsum) {
    __shared__ int sm[256];
    const int t = threadIdx.x, b = blockIdx.x;
    const int idx = b * 256 + t;
    const int v = (idx < NN) ? cnt[idx] : 0;
    sm[t] = v;
    __syncthreads();
#pragma unroll
    for (int off = 1; off < 256; off <<= 1) {
        const int y = (t >= off) ? sm[t - off] : 0;
        __syncthreads();
        sm[t] += y;
        __syncthreads();
    }
    if (idx < NN) rs[idx] = sm[t] - v;
    if (t == 255) bsum[b] = sm[255];
}

__global__ __launch_bounds__(256) void scan2_k(const int* __restrict__ bsum,
                                               int* __restrict__ bpre, int* __restrict__ rs) {
    __shared__ int sm[256];
    const int t = threadIdx.x;
    const int v = (t < SCAN_B) ? bsum[t] : 0;
    sm[t] = v;
    __syncthreads();
#pragma unroll
    for (int off = 1; off < 256; off <<= 1) {
        const int y = (t >= off) ? sm[t - off] : 0;
        __syncthreads();
        sm[t] += y;
        __syncthreads();
    }
    if (t < SCAN_B) bpre[t] = sm[t] - v;
    if (t == 255) rs[NN] = sm[255];
}

__global__ __launch_bounds__(256) void scan3_k(int* __restrict__ rs, const int* __restrict__ bpre,
                                               int* __restrict__ cursor) {
    const int idx = blockIdx.x * 256 + threadIdx.x;
    if (idx < NN) {
        rs[idx] += bpre[blockIdx.x];
        cursor[idx] = 0;
    }
}

__global__ void place_k(const int* __restrict__ src, const int* __restrict__ dst,
                        const int* __restrict__ rs, int* __restrict__ cursor,
                        int* __restrict__ elist) {
    const int e = blockIdx.x * 256 + threadIdx.x;
    if (e < NE) {
        const int d = dst[e];
        const int p = atomicAdd(&cursor[d], 1);
        elist[rs[d] + p] = src[e];
    }
}

// ---------------- gather1: h1 = relu(mean y1l[nbr] + b + y1r) into y1 cols 128..256 ----
__global__ __launch_bounds__(256) void gather1_k(u16* y1, const int* __restrict__ rs,
                                                 const int* __restrict__ elist,
                                                 const float* __restrict__ b1l) {
    const int t = threadIdx.x;
    const int n = blockIdx.x * 4 + (t >> 6);
    const int lane = t & 63;
    const int s0 = rs[n], s1 = rs[n + 1];
    float a0 = 0.f, a1 = 0.f;
    for (int j = s0; j < s1; j++) {
        const int s = elist[j];
        const u32 v = *(const u32*)(y1 + (size_t)s * 256 + lane * 2);
        a0 += bflo(v);
        a1 += bfhi(v);
    }
    const float inv = 1.f / fmaxf((float)(s1 - s0), 1.f);
    u16* hp = y1 + (size_t)n * 256 + 128 + lane * 2;
    const u32 r = *(const u32*)hp;
    const float h0 = fmaxf(fmaf(a0, inv, b1l[lane * 2] + bflo(r)), 0.f);
    const float h1 = fmaxf(fmaf(a1, inv, b1l[lane * 2 + 1] + bfhi(r)), 0.f);
    *(u32*)hp = (u32)f2bf(h0) | ((u32)f2bf(h1) << 16);
}

// ---------------- gather2: h2[NN,32] fp32 = relu(mean y2l[nbr] + b + y2r) --------------
__global__ __launch_bounds__(256) void gather2_k(const float* __restrict__ y2,
                                                 const int* __restrict__ rs,
                                                 const int* __restrict__ elist,
                                                 const float* __restrict__ b2l,
                                                 float* __restrict__ h2) {
    const int t = threadIdx.x;
    const int n = blockIdx.x * 8 + (t >> 5);
    const int lane = t & 31;
    const int s0 = rs[n], s1 = rs[n + 1];
    float a = 0.f;
    for (int j = s0; j < s1; j++) {
        const int s = elist[j];
        a += y2[(size_t)s * 64 + lane];
    }
    const float inv = 1.f / fmaxf((float)(s1 - s0), 1.f);
    h2[(size_t)n * 32 + lane] = fmaxf(fmaf(a, inv, b2l[lane] + y2[(size_t)n * 64 + 32 + lane]), 0.f);
}

__device__ __forceinline__ float leaky(float v) { return v > 0.f ? v : 0.1f * v; }

// ---------------- pool + MLP head, one block per graph ----------------
__global__ __launch_bounds__(256) void poolmlp_k(const float* __restrict__ h2,
                                                 const int* __restrict__ batch,
                                                 const float* __restrict__ Wl1, const float* __restrict__ bl1,
                                                 const float* __restrict__ Wl2, const float* __restrict__ bl2,
                                                 const float* __restrict__ Wd1, const float* __restrict__ bd1,
                                                 const float* __restrict__ Wd2, const float* __restrict__ bd2,
                                                 const float* __restrict__ Wd3, const float* __restrict__ bd3,
                                                 float* __restrict__ out) {
    __shared__ float red[256];
    __shared__ float bufA[32];
    __shared__ float bufB[32];
    const int g = blockIdx.x;
    const int t = threadIdx.x;
    int s, e;
    {
        int lo = 0, hi = NN;
        while (lo < hi) { const int m = (lo + hi) >> 1; if (batch[m] < g) lo = m + 1; else hi = m; }
        s = lo;
        lo = 0; hi = NN;
        while (lo < hi) { const int m = (lo + hi) >> 1; if (batch[m] < g + 1) lo = m + 1; else hi = m; }
        e = lo;
    }
    const int f = t & 31, grp = t >> 5;
    float acc = 0.f;
    for (int n = s + grp; n < e; n += 8) acc += h2[(size_t)n * 32 + f];
    red[t] = acc;
    __syncthreads();
    if (t < 32) {
        float sum = 0.f;
#pragma unroll
        for (int k = 0; k < 8; k++) sum += red[f + 32 * k];
        bufA[f] = sum / fmaxf((float)(e - s), 1.f);
    }
    __syncthreads();
    if (t < 32) {
        float sacc = bl1[t];
#pragma unroll
        for (int k = 0; k < 32; k++) sacc = fmaf(bufA[k], Wl1[k * 32 + t], sacc);
        bufB[t] = fmaxf(sacc, 0.f);
    }
    __syncthreads();
    if (t < 16) {
        float sacc = bl2[t];
#pragma unroll
        for (int k = 0; k < 32; k++) sacc = fmaf(bufB[k], Wl2[k * 16 + t], sacc);
        const float ev = leaky(sacc);
        bufA[t] = ev;
        out[g * 16 + t] = ev;
    }
    __syncthreads();
    if (t < 32) {
        float sacc = bd1[t];
#pragma unroll
        for (int k = 0; k < 16; k++) sacc = fmaf(bufA[k], Wd1[k * 32 + t], sacc);
        bufB[t] = leaky(sacc);
    }
    __syncthreads();
    if (t < 32) {
        float sacc = bd2[t];
#pragma unroll
        for (int k = 0; k < 32; k++) sacc = fmaf(bufB[k], Wd2[k * 32 + t], sacc);
        bufA[t] = leaky(sacc);
    }
    __syncthreads();
    if (t < 50) {
        float sacc = bd3[t];
#pragma unroll
        for (int k = 0; k < 32; k++) sacc = fmaf(bufA[k], Wd3[k * 50 + t], sacc);
        out[1024 + g * 50 + t] = sacc;
    }
}

extern "C" void kernel_launch(void* const* d_in, const int* in_sizes, int n_in,
                              void* d_out, int out_size, void* d_ws, size_t ws_size,
                              hipStream_t stream) {
    const float* x = (const float*)d_in[0];
    const int* ei = (const int*)d_in[1];
    const int* src = ei;
    const int* dst = ei + NE;
    const int* batch = (const int*)d_in[2];
    const float* W1l = (const float*)d_in[3];
    const float* b1l = (const float*)d_in[4];
    const float* W1r = (const float*)d_in[5];
    const float* W2l = (const float*)d_in[6];
    const float* b2l = (const float*)d_in[7];
    const float* W2r = (const float*)d_in[8];
    const float* Wl1 = (const float*)d_in[9];
    const float* bl1 = (const float*)d_in[10];
    const float* Wl2 = (const float*)d_in[11];
    const float* bl2 = (const float*)d_in[12];
    const float* Wd1 = (const float*)d_in[13];
    const float* bd1 = (const float*)d_in[14];
    const float* Wd2 = (const float*)d_in[15];
    const float* bd2 = (const float*)d_in[16];
    const float* Wd3 = (const float*)d_in[17];
    const float* bd3 = (const float*)d_in[18];

    char* W = (char*)d_ws;
    float* y2 = (float*)W;                     // 12.8M
    float* h2 = (float*)(W + 12800000);        // 6.4M
    u16* y1 = (u16*)(W + 51200000);            // 25.6M  [NN,256] bf16; cols 128..256 become h1
    u16* Wt1r = (u16*)(W + 76800000);          // 262144
    u16* Wt2r = (u16*)(W + 77062144);          // 16384
    int* rs = (int*)(W + 77078528);            // NN+1
    int* cursor = (int*)(W + 77278532);        // NN
    int* elist = (int*)(W + 77478532);         // NE
    int* bsum = (int*)(W + 79078532);          // SCAN_B
    int* bpre = (int*)(W + 79079316);          // SCAN_B

    // --- CSR build ---
    hipMemsetAsync(cursor, 0, (size_t)NN * 4, stream);
    cnt_k<<<(NE + 255) / 256, 256, 0, stream>>>(dst, cursor);
    scan1_k<<<SCAN_B, 256, 0, stream>>>(cursor, rs, bsum);
    scan2_k<<<1, 256, 0, stream>>>(bsum, bpre, rs);
    scan3_k<<<SCAN_B, 256, 0, stream>>>(rs, bpre, cursor);  // also zeros cursor
    place_k<<<(NE + 255) / 256, 256, 0, stream>>>(src, dst, rs, cursor, elist);

    // --- weight packing (GEMM-ready layouts) ---
    prepw_k<<<544, 256, 0, stream>>>(W1l, W1r, W2l, W2r, Wt1r, Wt2r);

    // --- layer 1 (cast fused into GEMM, pipelined) ---
    gemm1_mfma<<<dim3(391, 2), 256, 0, stream>>>(x, Wt1r, y1);
    gather1_k<<<12500, 256, 0, stream>>>(y1, rs, elist, b1l);

    // --- layer 2 ---
    gemm2_mfma<<<391, 256, 0, stream>>>(y1, Wt2r, y2);
    gather2_k<<<6250, 256, 0, stream>>>(y2, rs, elist, b2l, h2);

    // --- pool + MLP head ---
    poolmlp_k<<<NG, 256, 0, stream>>>(h2, batch, Wl1, bl1, Wl2, bl2,
                                      Wd1, bd1, Wd2, bd2, Wd3, bd3, (float*)d_out);
}

// Round 8
// 373.163 us; speedup vs baseline: 4.6094x; 1.0110x over previous
//
#include <hip/hip_runtime.h>

#define NN 50000
#define NE 400000
#define NG 64
#define SCAN_B 196  // ceil(NN/256)

typedef unsigned short u16;
typedef unsigned int u32;
typedef short short8 __attribute__((ext_vector_type(8)));
typedef float floatx4 __attribute__((ext_vector_type(4)));

__device__ __forceinline__ u16 f2bf(float f) {  // RNE
    union { float f; u32 u; } v; v.f = f;
    return (u16)((v.u + 0x7fff + ((v.u >> 16) & 1)) >> 16);
}
__device__ __forceinline__ float bflo(u32 p) { union { u32 u; float f; } v; v.u = p << 16; return v.f; }
__device__ __forceinline__ float bfhi(u32 p) { union { u32 u; float f; } v; v.u = p & 0xffff0000u; return v.f; }

#define GLD16(g, l) __builtin_amdgcn_global_load_lds( \
    (const __attribute__((address_space(1))) void*)(g), \
    (__attribute__((address_space(3))) void*)(l), 16, 0, 0)

// ---- pack weights into GEMM-ready chunk-contiguous layouts ----
// Wt1r[cb][ks][q][c][j]  (cb:2, ks:16, q:4, c:128, j:8), k=ks*32+q*8+j, col=cb*128+c
// Wt2r[q][c][j]          (q:16, c:64, j:8),              k=q*8+j,       col=c
__global__ __launch_bounds__(256) void prepw_k(const float* __restrict__ W1l,
                                               const float* __restrict__ W1r,
                                               const float* __restrict__ W2l,
                                               const float* __restrict__ W2r,
                                               u16* __restrict__ Wt1r,
                                               u16* __restrict__ Wt2r) {
    const int gid = blockIdx.x * 256 + threadIdx.x;  // 139264 total
    if (gid < 131072) {
        const int j = gid & 7, c = (gid >> 3) & 127, q = (gid >> 10) & 3;
        const int ks = (gid >> 12) & 15, cb = gid >> 16;
        const int k = ks * 32 + q * 8 + j;
        const int col = cb * 128 + c;
        const float v = (col < 128) ? W1l[k * 128 + col] : W1r[k * 128 + (col - 128)];
        Wt1r[gid] = f2bf(v);
    } else {
        const int g2 = gid - 131072;  // 8192
        const int j = g2 & 7, c = (g2 >> 3) & 63, q = g2 >> 9;
        const int k = q * 8 + j;
        const float v = (c < 32) ? W2l[k * 32 + c] : W2r[k * 32 + (c - 32)];
        Wt2r[g2] = f2bf(v);
    }
}

// ---------------- GEMM1 (MFMA, fused fp32->bf16 cast): x[NN,512] @ W^T -> y1[NN,256] bf16
// tile 64x128, grid (782,2), 4 waves (2x2 of 32x64), BK=32, LDS chunk-major [q][row].
// Small tile -> 1564 blocks ~ 6 blocks/CU: latency hidden by TLP, not pipelining.
__global__ __launch_bounds__(256) void gemm1_mfma(const float* __restrict__ x,
                                                  const u16* __restrict__ Wt,
                                                  u16* __restrict__ y1) {
    __shared__ u16 lA[2048];  // [q 0..3][r 0..63] x 8 (4 KB)
    __shared__ u16 lB[4096];  // [q 0..3][c 0..127] x 8 (8 KB)
    const int t = threadIdx.x, wave = t >> 6, lane = t & 63;
    const int row0 = blockIdx.x * 64, cb = blockIdx.y;
    const int wr = wave >> 1, wc = wave & 1;
    const int q4 = lane >> 4, r16 = lane & 15;
    // per-thread A item: row = t>>2 (0..63), q = t&3
    const int arow = t >> 2, aq = t & 3;
    int grow = row0 + arow; if (grow > NN - 1) grow = NN - 1;
    const float* xp0 = x + (size_t)grow * 512 + aq * 8;

    floatx4 acc[2][4] = {};
    for (int ks = 0; ks < 16; ks++) {
        // B: wave w stages its q=w plane (128 cols), fully coalesced 2x1KB
        const u16* bsrc = Wt + ((size_t)(((cb * 16 + ks) * 4 + wave) * 128)) * 8;
        GLD16(bsrc + (size_t)lane * 8, &lB[(wave * 128) * 8]);
        GLD16(bsrc + (size_t)(64 + lane) * 8, &lB[(wave * 128 + 64) * 8]);
        // A: fp32 load + in-reg cast + one ds_write_b128 per thread
        {
            const float* xp = xp0 + ks * 32;
            const float4 f0 = *(const float4*)xp;
            const float4 f1 = *(const float4*)(xp + 4);
            uint4 p;
            p.x = f2bf(f0.x) | ((u32)f2bf(f0.y) << 16);
            p.y = f2bf(f0.z) | ((u32)f2bf(f0.w) << 16);
            p.z = f2bf(f1.x) | ((u32)f2bf(f1.y) << 16);
            p.w = f2bf(f1.z) | ((u32)f2bf(f1.w) << 16);
            *(uint4*)&lA[(aq * 64 + arow) * 8] = p;
        }
        __builtin_amdgcn_s_waitcnt(0);
        __syncthreads();
        short8 a[2], b[4];
#pragma unroll
        for (int i = 0; i < 2; i++) a[i] = *(const short8*)&lA[(q4 * 64 + wr * 32 + i * 16 + r16) * 8];
#pragma unroll
        for (int j = 0; j < 4; j++) b[j] = *(const short8*)&lB[(q4 * 128 + wc * 64 + j * 16 + r16) * 8];
#pragma unroll
        for (int i = 0; i < 2; i++)
#pragma unroll
            for (int j = 0; j < 4; j++)
                acc[i][j] = __builtin_amdgcn_mfma_f32_16x16x32_bf16(a[i], b[j], acc[i][j], 0, 0, 0);
        __syncthreads();
    }
#pragma unroll
    for (int i = 0; i < 2; i++) {
        const int row = row0 + wr * 32 + i * 16 + q4 * 4;
#pragma unroll
        for (int j = 0; j < 4; j++) {
            const int col = cb * 128 + wc * 64 + j * 16 + r16;
#pragma unroll
            for (int rg = 0; rg < 4; rg++) {
                if (row + rg < NN) y1[(size_t)(row + rg) * 256 + col] = f2bf(acc[i][j][rg]);
            }
        }
    }
}

// ---------------- GEMM2 (MFMA): h1 (y1 cols 128..256) @ Wt2r -> y2[NN,64] fp32 -------
// tile 64x64, grid 782, whole K=128 staged once, 4 waves (2x2 of 32x32).
__global__ __launch_bounds__(256) void gemm2_mfma(const u16* __restrict__ y1,
                                                  const u16* __restrict__ Wt2r,
                                                  float* __restrict__ y2) {
    __shared__ u16 lA[8192];  // [q 0..15][r 0..63] x 8 (16 KB)
    __shared__ u16 lB[8192];  // [q 0..15][c 0..63] x 8 (16 KB)
    const int t = threadIdx.x, wave = t >> 6, lane = t & 63;
    const int row0 = blockIdx.x * 64;
    const int wr = wave >> 1, wc = wave & 1;
    const int q4 = lane >> 4, r16 = lane & 15;
#pragma unroll
    for (int s = 0; s < 4; s++) {
        const int i = s * 256 + t;          // 0..1023
        const int iq = i >> 6, r = i & 63;  // q-chunk, row
        int grow = row0 + r; if (grow > NN - 1) grow = NN - 1;
        GLD16(y1 + (size_t)grow * 256 + 128 + iq * 8, &lA[(iq * 64 + r) * 8]);
    }
#pragma unroll
    for (int s = 0; s < 4; s++) {
        const int qq = wave * 4 + s;
        GLD16(Wt2r + (size_t)(qq * 64) * 8 + (size_t)lane * 8, &lB[qq * 64 * 8]);
    }
    __builtin_amdgcn_s_waitcnt(0);
    __syncthreads();
    floatx4 acc[2][2] = {};
#pragma unroll
    for (int ks = 0; ks < 4; ks++) {
        const int qk = ks * 4 + q4;
        short8 a[2], b[2];
#pragma unroll
        for (int i = 0; i < 2; i++) a[i] = *(const short8*)&lA[(qk * 64 + wr * 32 + i * 16 + r16) * 8];
#pragma unroll
        for (int j = 0; j < 2; j++) b[j] = *(const short8*)&lB[(qk * 64 + wc * 32 + j * 16 + r16) * 8];
#pragma unroll
        for (int i = 0; i < 2; i++)
#pragma unroll
            for (int j = 0; j < 2; j++)
                acc[i][j] = __builtin_amdgcn_mfma_f32_16x16x32_bf16(a[i], b[j], acc[i][j], 0, 0, 0);
    }
#pragma unroll
    for (int i = 0; i < 2; i++) {
        const int row = row0 + wr * 32 + i * 16 + q4 * 4;
#pragma unroll
        for (int j = 0; j < 2; j++) {
            const int col = wc * 32 + j * 16 + r16;
#pragma unroll
            for (int rg = 0; rg < 4; rg++) {
                if (row + rg < NN) y2[(size_t)(row + rg) * 64 + col] = acc[i][j][rg];
            }
        }
    }
}

// ---------------- CSR build ----------------
__global__ void cnt_k(const int* __restrict__ dst, int* __restrict__ cnt) {
    const int e = blockIdx.x * 256 + threadIdx.x;
    if (e < NE) atomicAdd(&cnt[dst[e]], 1);
}

__global__ __launch_bounds__(256) void scan1_k(const int* __restrict__ cnt,
                                               int* __restrict__ rs, int* __restrict__ bsum) {
    __shared__ int sm[256];
    const int t = threadIdx.x, b = blockIdx.x;
    const int idx = b * 256 + t;
    const int v = (idx < NN) ? cnt[idx] : 0;
    sm[t] = v;
    __syncthreads();
#pragma unroll
    for (int off = 1; off < 256; off <<= 1) {
        const int y = (t >= off) ? sm[t - off] : 0;
        __syncthreads();
        sm[t] += y;
        __syncthreads();
    }
    if (idx < NN) rs[idx] = sm[t] - v;
    if (t == 255) bsum[b] = sm[255];
}

__global__ __launch_bounds__(256) void scan2_k(const int* __restrict__ bsum,
                                               int* __restrict__ bpre, int* __restrict__ rs) {
    __shared__ int sm[256];
    const int t = threadIdx.x;
    const int v = (t < SCAN_B) ? bsum[t] : 0;
    sm[t] = v;
    __syncthreads();
#pragma unroll
    for (int off = 1; off < 256; off <<= 1) {
        const int y = (t >= off) ? sm[t - off] : 0;
        __syncthreads();
        sm[t] += y;
        __syncthreads();
    }
    if (t < SCAN_B) bpre[t] = sm[t] - v;
    if (t == 255) rs[NN] = sm[255];
}

__global__ __launch_bounds__(256) void scan3_k(int* __restrict__ rs, const int* __restrict__ bpre,
                                               int* __restrict__ cursor) {
    const int idx = blockIdx.x * 256 + threadIdx.x;
    if (idx < NN) {
        rs[idx] += bpre[blockIdx.x];
        cursor[idx] = 0;
    }
}

__global__ void place_k(const int* __restrict__ src, const int* __restrict__ dst,
                        const int* __restrict__ rs, int* __restrict__ cursor,
                        int* __restrict__ elist) {
    const int e = blockIdx.x * 256 + threadIdx.x;
    if (e < NE) {
        const int d = dst[e];
        const int p = atomicAdd(&cursor[d], 1);
        elist[rs[d] + p] = src[e];
    }
}

// ---------------- gather1: h1 = relu(mean y1l[nbr] + b + y1r) into y1 cols 128..256 ----
__global__ __launch_bounds__(256) void gather1_k(u16* y1, const int* __restrict__ rs,
                                                 const int* __restrict__ elist,
                                                 const float* __restrict__ b1l) {
    const int t = threadIdx.x;
    const int n = blockIdx.x * 4 + (t >> 6);
    const int lane = t & 63;
    const int s0 = rs[n], s1 = rs[n + 1];
    float a0 = 0.f, a1 = 0.f;
    for (int j = s0; j < s1; j++) {
        const int s = elist[j];
        const u32 v = *(const u32*)(y1 + (size_t)s * 256 + lane * 2);
        a0 += bflo(v);
        a1 += bfhi(v);
    }
    const float inv = 1.f / fmaxf((float)(s1 - s0), 1.f);
    u16* hp = y1 + (size_t)n * 256 + 128 + lane * 2;
    const u32 r = *(const u32*)hp;
    const float h0 = fmaxf(fmaf(a0, inv, b1l[lane * 2] + bflo(r)), 0.f);
    const float h1 = fmaxf(fmaf(a1, inv, b1l[lane * 2 + 1] + bfhi(r)), 0.f);
    *(u32*)hp = (u32)f2bf(h0) | ((u32)f2bf(h1) << 16);
}

// ---------------- gather2: h2[NN,32] fp32 = relu(mean y2l[nbr] + b + y2r) --------------
__global__ __launch_bounds__(256) void gather2_k(const float* __restrict__ y2,
                                                 const int* __restrict__ rs,
                                                 const int* __restrict__ elist,
                                                 const float* __restrict__ b2l,
                                                 float* __restrict__ h2) {
    const int t = threadIdx.x;
    const int n = blockIdx.x * 8 + (t >> 5);
    const int lane = t & 31;
    const int s0 = rs[n], s1 = rs[n + 1];
    float a = 0.f;
    for (int j = s0; j < s1; j++) {
        const int s = elist[j];
        a += y2[(size_t)s * 64 + lane];
    }
    const float inv = 1.f / fmaxf((float)(s1 - s0), 1.f);
    h2[(size_t)n * 32 + lane] = fmaxf(fmaf(a, inv, b2l[lane] + y2[(size_t)n * 64 + 32 + lane]), 0.f);
}

__device__ __forceinline__ float leaky(float v) { return v > 0.f ? v : 0.1f * v; }

// ---------------- pool + MLP head, one block per graph ----------------
__global__ __launch_bounds__(256) void poolmlp_k(const float* __restrict__ h2,
                                                 const int* __restrict__ batch,
                                                 const float* __restrict__ Wl1, const float* __restrict__ bl1,
                                                 const float* __restrict__ Wl2, const float* __restrict__ bl2,
                                                 const float* __restrict__ Wd1, const float* __restrict__ bd1,
                                                 const float* __restrict__ Wd2, const float* __restrict__ bd2,
                                                 const float* __restrict__ Wd3, const float* __restrict__ bd3,
                                                 float* __restrict__ out) {
    __shared__ float red[256];
    __shared__ float bufA[32];
    __shared__ float bufB[32];
    const int g = blockIdx.x;
    const int t = threadIdx.x;
    int s, e;
    {
        int lo = 0, hi = NN;
        while (lo < hi) { const int m = (lo + hi) >> 1; if (batch[m] < g) lo = m + 1; else hi = m; }
        s = lo;
        lo = 0; hi = NN;
        while (lo < hi) { const int m = (lo + hi) >> 1; if (batch[m] < g + 1) lo = m + 1; else hi = m; }
        e = lo;
    }
    const int f = t & 31, grp = t >> 5;
    float acc = 0.f;
    for (int n = s + grp; n < e; n += 8) acc += h2[(size_t)n * 32 + f];
    red[t] = acc;
    __syncthreads();
    if (t < 32) {
        float sum = 0.f;
#pragma unroll
        for (int k = 0; k < 8; k++) sum += red[f + 32 * k];
        bufA[f] = sum / fmaxf((float)(e - s), 1.f);
    }
    __syncthreads();
    if (t < 32) {
        float sacc = bl1[t];
#pragma unroll
        for (int k = 0; k < 32; k++) sacc = fmaf(bufA[k], Wl1[k * 32 + t], sacc);
        bufB[t] = fmaxf(sacc, 0.f);
    }
    __syncthreads();
    if (t < 16) {
        float sacc = bl2[t];
#pragma unroll
        for (int k = 0; k < 32; k++) sacc = fmaf(bufB[k], Wl2[k * 16 + t], sacc);
        const float ev = leaky(sacc);
        bufA[t] = ev;
        out[g * 16 + t] = ev;
    }
    __syncthreads();
    if (t < 32) {
        float sacc = bd1[t];
#pragma unroll
        for (int k = 0; k < 16; k++) sacc = fmaf(bufA[k], Wd1[k * 32 + t], sacc);
        bufB[t] = leaky(sacc);
    }
    __syncthreads();
    if (t < 32) {
        float sacc = bd2[t];
#pragma unroll
        for (int k = 0; k < 32; k++) sacc = fmaf(bufB[k], Wd2[k * 32 + t], sacc);
        bufA[t] = leaky(sacc);
    }
    __syncthreads();
    if (t < 50) {
        float sacc = bd3[t];
#pragma unroll
        for (int k = 0; k < 32; k++) sacc = fmaf(bufA[k], Wd3[k * 50 + t], sacc);
        out[1024 + g * 50 + t] = sacc;
    }
}

extern "C" void kernel_launch(void* const* d_in, const int* in_sizes, int n_in,
                              void* d_out, int out_size, void* d_ws, size_t ws_size,
                              hipStream_t stream) {
    const float* x = (const float*)d_in[0];
    const int* ei = (const int*)d_in[1];
    const int* src = ei;
    const int* dst = ei + NE;
    const int* batch = (const int*)d_in[2];
    const float* W1l = (const float*)d_in[3];
    const float* b1l = (const float*)d_in[4];
    const float* W1r = (const float*)d_in[5];
    const float* W2l = (const float*)d_in[6];
    const float* b2l = (const float*)d_in[7];
    const float* W2r = (const float*)d_in[8];
    const float* Wl1 = (const float*)d_in[9];
    const float* bl1 = (const float*)d_in[10];
    const float* Wl2 = (const float*)d_in[11];
    const float* bl2 = (const float*)d_in[12];
    const float* Wd1 = (const float*)d_in[13];
    const float* bd1 = (const float*)d_in[14];
    const float* Wd2 = (const float*)d_in[15];
    const float* bd2 = (const float*)d_in[16];
    const float* Wd3 = (const float*)d_in[17];
    const float* bd3 = (const float*)d_in[18];

    char* W = (char*)d_ws;
    float* y2 = (float*)W;                     // 12.8M
    float* h2 = (float*)(W + 12800000);        // 6.4M
    u16* y1 = (u16*)(W + 51200000);            // 25.6M  [NN,256] bf16; cols 128..256 become h1
    u16* Wt1r = (u16*)(W + 76800000);          // 262144
    u16* Wt2r = (u16*)(W + 77062144);          // 16384
    int* rs = (int*)(W + 77078528);            // NN+1
    int* cursor = (int*)(W + 77278532);        // NN
    int* elist = (int*)(W + 77478532);         // NE
    int* bsum = (int*)(W + 79078532);          // SCAN_B
    int* bpre = (int*)(W + 79079316);          // SCAN_B

    // --- CSR build ---
    hipMemsetAsync(cursor, 0, (size_t)NN * 4, stream);
    cnt_k<<<(NE + 255) / 256, 256, 0, stream>>>(dst, cursor);
    scan1_k<<<SCAN_B, 256, 0, stream>>>(cursor, rs, bsum);
    scan2_k<<<1, 256, 0, stream>>>(bsum, bpre, rs);
    scan3_k<<<SCAN_B, 256, 0, stream>>>(rs, bpre, cursor);  // also zeros cursor
    place_k<<<(NE + 255) / 256, 256, 0, stream>>>(src, dst, rs, cursor, elist);

    // --- weight packing (GEMM-ready layouts) ---
    prepw_k<<<544, 256, 0, stream>>>(W1l, W1r, W2l, W2r, Wt1r, Wt2r);

    // --- layer 1 (cast fused into GEMM) ---
    gemm1_mfma<<<dim3(782, 2), 256, 0, stream>>>(x, Wt1r, y1);
    gather1_k<<<12500, 256, 0, stream>>>(y1, rs, elist, b1l);

    // --- layer 2 ---
    gemm2_mfma<<<782, 256, 0, stream>>>(y1, Wt2r, y2);
    gather2_k<<<6250, 256, 0, stream>>>(y2, rs, elist, b2l, h2);

    // --- pool + MLP head ---
    poolmlp_k<<<NG, 256, 0, stream>>>(h2, batch, Wl1, bl1, Wl2, bl2,
                                      Wd1, bd1, Wd2, bd2, Wd3, bd3, (float*)d_out);
}